// Round 3
// baseline (344.831 us; speedup 1.0000x reference)
//
#include <hip/hip_runtime.h>

typedef __bf16 bf16;
typedef __attribute__((ext_vector_type(8))) __bf16 bf16x8;
typedef __attribute__((ext_vector_type(4))) float f32x4;
typedef __attribute__((ext_vector_type(16))) float f32x16;
typedef __attribute__((ext_vector_type(4))) unsigned short u16x4;
typedef __attribute__((ext_vector_type(2))) int v2i;

#define D_MODEL 1024
#define SEQ     2048
#define NB      4
#define NH      16
#define DK      64
#define MROWS   (NB * SEQ)   // 8192

#define MFMA_BF16 __builtin_amdgcn_mfma_f32_16x16x32_bf16
#define MFMA32    __builtin_amdgcn_mfma_f32_32x32x16_bf16
#define EXP2F(x) __builtin_amdgcn_exp2f(x)
#define QSCALE 0.18033688011112042f   // 0.125 * log2(e)

#define BARRIER() do { asm volatile("" ::: "memory"); \
                       __builtin_amdgcn_s_barrier();  \
                       asm volatile("" ::: "memory"); } while (0)

__device__ __forceinline__ bf16 f2b(float f) {
    union { float f; unsigned u; } c; c.f = f;
    unsigned r = (c.u + 0x7fffu + ((c.u >> 16) & 1u)) >> 16;
    union { unsigned short s; bf16 b; } o; o.s = (unsigned short)r;
    return o.b;
}
__device__ __forceinline__ unsigned short f2u(float f) {
    union { float f; unsigned u; } c; c.f = f;
    return (unsigned short)((c.u + 0x7fffu + ((c.u >> 16) & 1u)) >> 16);
}

__device__ __forceinline__ f32x16 zero16() {
    f32x16 z = {0.f,0.f,0.f,0.f,0.f,0.f,0.f,0.f,
                0.f,0.f,0.f,0.f,0.f,0.f,0.f,0.f};
    return z;
}

template <int N> struct IC { static constexpr int v = N; };

// ---------------------------------------------------------------- prep (fused)
__global__ void prep_kernel(const float* __restrict__ X,
                            const float* __restrict__ Wq, const float* __restrict__ Wk,
                            const float* __restrict__ Wv, const float* __restrict__ Wo,
                            bf16* __restrict__ Xb, bf16* __restrict__ WqkvT,
                            bf16* __restrict__ WoT) {
    __shared__ float tile[32][33];
    const int bid = blockIdx.x;
    if (bid < 8192) {
        int i = bid * 256 + threadIdx.x;
        float4 v = ((const float4*)X)[i];
        u16x4 o; o[0] = f2u(v.x); o[1] = f2u(v.y); o[2] = f2u(v.z); o[3] = f2u(v.w);
        ((u16x4*)Xb)[i] = o;
    } else {
        int r = bid - 8192;
        int w = r >> 10, tl = r & 1023;
        const float* src = (w == 0) ? Wq : (w == 1) ? Wk : (w == 2) ? Wv : Wo;
        bf16* dst = (w == 3) ? WoT : WqkvT + (size_t)w * 1024 * 1024;
        const int n0 = (tl & 31) * 32, k0 = (tl >> 5) * 32;
        const int tx = threadIdx.x & 31, ty = threadIdx.x >> 5;
#pragma unroll
        for (int i = 0; i < 4; i++)
            tile[ty + i * 8][tx] = src[(size_t)(k0 + ty + i * 8) * 1024 + n0 + tx];
        __syncthreads();
#pragma unroll
        for (int i = 0; i < 4; i++)
            dst[(size_t)(n0 + ty + i * 8) * 1024 + k0 + tx] = f2b(tile[tx][ty + i * 8]);
    }
}

// ---------------------------------------------------------------- fused QKV GEMM
// R11: 256x256 8-phase schedule (T2 swizzled LDS + T3/T4 counted vmcnt + T5
// setprio), per the m201 template. 512 threads = 8 waves (2M x 4N), per-wave
// 128x64 output (acc 8x4 x 16x16 frags). BK=64, double-buffered 128 KiB LDS.
// Per K-tile: 4 phases; ds_reads concentrated in P0/P1 so both LDS buffers'
// read windows close at the P1 barrier; one half-tile (16KB) staged per phase:
//   P0: read af[0..3]+bfr[0..1] | stage K(t+1).B0 | quad(i0-3 x j0-1)
//   P1: read af[4..7]+bfr[2..3] | stage K(t+1).B1 | quad(i4-7 x j2-3)
//   P2:                           stage K(t+2).A0 | quad(i0-3 x j2-3)
//   P3:                           stage K(t+2).A1 | quad(i4-7 x j0-1), vmcnt
// Steady-state vmcnt(4) once per K-tile (outstanding = K(t+2).A halves);
// tail: kt==14 -> vmcnt(0) (K15.B just issued), kt==15 -> none.
__global__ __launch_bounds__(512, 2) void gemm_qkv(const bf16* __restrict__ A,
                                                   const bf16* __restrict__ Bt,
                                                   bf16* __restrict__ outQ,
                                                   bf16* __restrict__ outV) {
    __shared__ __align__(16) char lds[131072];  // [buf][A 32K | B 32K]

    const int t = threadIdx.x;
    const int wid = t >> 6, lane = t & 63;
    const int ln = lane & 15, qd = lane >> 4;
    const int wm = wid >> 2, wn = wid & 3;      // 2 x 4 wave grid
    const int swk = ln & 7;

    // 384 blocks: bijective XCD swizzle (384 % 8 == 0), col-major tile walk
    const int wg = (blockIdx.x & 7) * 48 + (blockIdx.x >> 3);
    const int rowb = wg & 31, colb = wg >> 5;   // 32 rows x 12 cols
    const int row0 = rowb * 256, col0 = colb * 256;
    const bool isQK = (col0 < 2048);

    // staging: global side pre-swizzled, LDS dest linear
    const int srow = t >> 3;                    // 0..63
    const int schunk = (t & 7) ^ (srow & 7);
    const bf16* ga = A  + (size_t)(row0 + srow) * 1024 + schunk * 8;
    const bf16* gb = Bt + (size_t)(col0 + srow) * 1024 + schunk * 8;

    // half-tile stage: 128 rows x 64 k = 16KB = 512 thr x 2 loads x 16B
    auto stageA = [&](int kt, int hc, int buf) {
#pragma unroll
        for (int L = 0; L < 2; L++)
            __builtin_amdgcn_global_load_lds(
                (const __attribute__((address_space(1))) void*)
                    (ga + (size_t)(hc * 128 + L * 64) * 1024 + kt * 64),
                (__attribute__((address_space(3))) void*)
                    (lds + buf * 65536 + hc * 16384 + L * 8192 + t * 16), 16, 0, 0);
    };
    auto stageB = [&](int kt, int hc, int buf) {
#pragma unroll
        for (int L = 0; L < 2; L++)
            __builtin_amdgcn_global_load_lds(
                (const __attribute__((address_space(1))) void*)
                    (gb + (size_t)(hc * 128 + L * 64) * 1024 + kt * 64),
                (__attribute__((address_space(3))) void*)
                    (lds + buf * 65536 + 32768 + hc * 16384 + L * 8192 + t * 16), 16, 0, 0);
    };

    // per-lane LDS read bases (XOR-swizzled chunk slots)
    const char* pABase = lds + (wm * 128 + ln) * 128;
    const char* pBBase = lds + 32768 + (wn * 64 + ln) * 128;
    const int cks0 = (qd ^ swk) * 16;
    const int cks1 = ((4 + qd) ^ swk) * 16;

    f32x4 acc[8][4];
#pragma unroll
    for (int i = 0; i < 8; i++)
#pragma unroll
        for (int j = 0; j < 4; j++) acc[i][j] = (f32x4){0.f, 0.f, 0.f, 0.f};

    // ---------------- prologue: K0.{A0,A1,B0,B1}, K1.{A0,A1}  (12 loads)
    stageA(0, 0, 0); stageA(0, 1, 0);
    stageB(0, 0, 0); stageB(0, 1, 0);
    stageA(1, 0, 1); stageA(1, 1, 1);
    asm volatile("s_waitcnt vmcnt(4)" ::: "memory");   // K0 landed; K1.A in flight
    BARRIER();

    auto ktile = [&](auto bufc, int kt) {
        constexpr int BUF = decltype(bufc)::v;
        const char* pa0 = pABase + BUF * 65536 + cks0;
        const char* pa1 = pABase + BUF * 65536 + cks1;
        const char* pb0 = pBBase + BUF * 65536 + cks0;
        const char* pb1 = pBBase + BUF * 65536 + cks1;

        bf16x8 af[8][2], bfr[4][2];

        auto quad = [&](int ih, int jh) {
            __builtin_amdgcn_s_setprio(1);
            if (isQK) {
#pragma unroll
                for (int i2 = 0; i2 < 4; i2++)
#pragma unroll
                    for (int j2 = 0; j2 < 2; j2++)
#pragma unroll
                        for (int ks = 0; ks < 2; ks++)
                            acc[ih * 4 + i2][jh * 2 + j2] =
                                MFMA_BF16(bfr[jh * 2 + j2][ks], af[ih * 4 + i2][ks],
                                          acc[ih * 4 + i2][jh * 2 + j2], 0, 0, 0);
            } else {
#pragma unroll
                for (int i2 = 0; i2 < 4; i2++)
#pragma unroll
                    for (int j2 = 0; j2 < 2; j2++)
#pragma unroll
                        for (int ks = 0; ks < 2; ks++)
                            acc[ih * 4 + i2][jh * 2 + j2] =
                                MFMA_BF16(af[ih * 4 + i2][ks], bfr[jh * 2 + j2][ks],
                                          acc[ih * 4 + i2][jh * 2 + j2], 0, 0, 0);
            }
            __builtin_amdgcn_s_setprio(0);
        };

        // ---- P0: read af[0..3], bfr[0..1]; stage K(t+1).B0; quad(0,0)
#pragma unroll
        for (int i = 0; i < 4; i++) {
            af[i][0] = *(const bf16x8*)(pa0 + i * 2048);
            af[i][1] = *(const bf16x8*)(pa1 + i * 2048);
        }
#pragma unroll
        for (int j = 0; j < 2; j++) {
            bfr[j][0] = *(const bf16x8*)(pb0 + j * 2048);
            bfr[j][1] = *(const bf16x8*)(pb1 + j * 2048);
        }
        if (kt + 1 < 16) stageB(kt + 1, 0, BUF ^ 1);
        asm volatile("s_waitcnt lgkmcnt(8)" ::: "memory");
        BARRIER();
        asm volatile("s_waitcnt lgkmcnt(0)" ::: "memory");
        quad(0, 0);
        BARRIER();

        // ---- P1: read af[4..7], bfr[2..3]; stage K(t+1).B1; quad(1,1)
#pragma unroll
        for (int i = 0; i < 4; i++) {
            af[4 + i][0] = *(const bf16x8*)(pa0 + (4 + i) * 2048);
            af[4 + i][1] = *(const bf16x8*)(pa1 + (4 + i) * 2048);
        }
#pragma unroll
        for (int j = 0; j < 2; j++) {
            bfr[2 + j][0] = *(const bf16x8*)(pb0 + (2 + j) * 2048);
            bfr[2 + j][1] = *(const bf16x8*)(pb1 + (2 + j) * 2048);
        }
        if (kt + 1 < 16) stageB(kt + 1, 1, BUF ^ 1);
        asm volatile("s_waitcnt lgkmcnt(8)" ::: "memory");
        BARRIER();
        asm volatile("s_waitcnt lgkmcnt(0)" ::: "memory");
        quad(1, 1);
        BARRIER();

        // ---- P2: stage K(t+2).A0 (buf free: reads ended at P1 barrier); quad(0,1)
        if (kt + 2 < 16) stageA(kt + 2, 0, BUF);
        BARRIER();
        quad(0, 1);
        BARRIER();

        // ---- P3: stage K(t+2).A1; quad(1,0); counted vmcnt; barrier
        if (kt + 2 < 16) stageA(kt + 2, 1, BUF);
        BARRIER();
        quad(1, 0);
        if (kt + 2 < 16) {
            asm volatile("s_waitcnt vmcnt(4)" ::: "memory");  // allow K(t+2).A in flight
        } else if (kt + 1 < 16) {
            asm volatile("s_waitcnt vmcnt(0)" ::: "memory");  // K15.B must land
        }
        BARRIER();
    };

#pragma unroll 1
    for (int kt = 0; kt < 16; kt += 2) {
        ktile(IC<0>{}, kt);
        ktile(IC<1>{}, kt + 1);
    }

    // ---------------- epilogue
    if (isQK) {
#pragma unroll
        for (int i = 0; i < 8; i++)
#pragma unroll
            for (int j = 0; j < 4; j++) {
                int m  = row0 + wm * 128 + i * 16 + ln;
                int n0 = col0 + wn * 64 + j * 16 + qd * 4;
                float scale = (n0 < 1024) ? QSCALE : 1.0f;
                int b = m >> 11, s = m & 2047;
                int h = (n0 & 1023) >> 6, d0 = n0 & 63;
                size_t addr = (((size_t)(b * NH + h) * SEQ + s) * DK + d0)
                              + (size_t)(n0 >> 10) * 8388608;
                u16x4 w;
#pragma unroll
                for (int r = 0; r < 4; r++) w[r] = f2u(acc[i][j][r] * scale);
                *(u16x4*)&outQ[addr] = w;
            }
    } else {
#pragma unroll
        for (int i = 0; i < 8; i++)
#pragma unroll
            for (int j = 0; j < 4; j++) {
                int m0 = row0 + wm * 128 + i * 16 + qd * 4;
                int n  = col0 + wn * 64 + j * 16 + ln - 2048;
                int b = m0 >> 11, s0 = m0 & 2047;
                int h = n >> 6, d = n & 63;
                size_t addr = ((size_t)(b * NH + h) * DK + d) * SEQ + s0;
                u16x4 w;
#pragma unroll
                for (int r = 0; r < 4; r++) w[r] = f2u(acc[i][j][r]);
                *(u16x4*)&outV[addr] = w;
            }
    }
}

// ---------------------------------------------------------------- output GEMM
__global__ __launch_bounds__(256) void gemm_o(const bf16* __restrict__ A,
                                              const bf16* __restrict__ Bt,
                                              float* __restrict__ out) {
    __shared__ __align__(16) bf16 lA[128 * 64];
    __shared__ __align__(16) bf16 lB[128 * 64];

    const int t = threadIdx.x;
    const int wid = t >> 6, lane = t & 63;
    const int ln = lane & 15, qd = lane >> 4;
    const int wm = wid >> 1, wn = wid & 1;

    const int bid = blockIdx.x;
    const int colb = bid & 7, rowb = bid >> 3;
    const int row0 = rowb * 128, col0 = colb * 128;

    const int srow = t >> 3;
    const int schunk = (t & 7) ^ (srow & 7);
    const bf16* ga = A  + (size_t)(row0 + srow) * 1024 + schunk * 8;
    const bf16* gb = Bt + (size_t)(col0 + srow) * 1024 + schunk * 8;
    const int swk = ln & 7;

    f32x4 acc[4][4];
#pragma unroll
    for (int i = 0; i < 4; i++)
#pragma unroll
        for (int j = 0; j < 4; j++) acc[i][j] = (f32x4){0.f, 0.f, 0.f, 0.f};

    for (int kb = 0; kb < 1024; kb += 64) {
#pragma unroll
        for (int c = 0; c < 4; c++) {
            __builtin_amdgcn_global_load_lds(
                (const __attribute__((address_space(1))) void*)(ga + kb + (size_t)c * 32 * 1024),
                (__attribute__((address_space(3))) void*)(&lA[t * 8 + c * 2048]), 16, 0, 0);
            __builtin_amdgcn_global_load_lds(
                (const __attribute__((address_space(1))) void*)(gb + kb + (size_t)c * 32 * 1024),
                (__attribute__((address_space(3))) void*)(&lB[t * 8 + c * 2048]), 16, 0, 0);
        }
        __syncthreads();

#pragma unroll
        for (int ks = 0; ks < 2; ks++) {
            bf16x8 af[4], bfr[4];
#pragma unroll
            for (int i = 0; i < 4; i++)
                af[i] = *(const bf16x8*)&lA[(wm * 64 + i * 16 + ln) * 64
                                            + ((ks * 4 + qd) ^ swk) * 8];
#pragma unroll
            for (int j = 0; j < 4; j++)
                bfr[j] = *(const bf16x8*)&lB[(wn * 64 + j * 16 + ln) * 64
                                             + ((ks * 4 + qd) ^ swk) * 8];
#pragma unroll
            for (int i = 0; i < 4; i++)
#pragma unroll
                for (int j = 0; j < 4; j++)
                    acc[i][j] = MFMA_BF16(bfr[j], af[i], acc[i][j], 0, 0, 0);
        }
        __syncthreads();
    }

#pragma unroll
    for (int i = 0; i < 4; i++)
#pragma unroll
        for (int j = 0; j < 4; j++) {
            int m  = row0 + wm * 64 + i * 16 + ln;
            int n0 = col0 + wn * 64 + j * 16 + qd * 4;
            *(f32x4*)&out[(size_t)m * 1024 + n0] = acc[i][j];
        }
}

// ---------------------------------------------------------------- attention
// R10 structure (unchanged): 32x32 MFMA, in-register softmax via
// cvt_pk_bf16 + permlane32_swap, 64-row q-groups paired (g, 31-g),
// 128-thread blocks, wave-uniform full/edge specialization.
__global__ __launch_bounds__(128, 2) void attn_kernel(const bf16* __restrict__ Q,
                                                      const bf16* __restrict__ K,
                                                      const bf16* __restrict__ Vt,
                                                      bf16* __restrict__ attn_out) {
    // layout: K buf0 | K buf1 | V buf0 | V buf1   (8 KB each)
    __shared__ __align__(16) bf16 smem[4][64 * 64];

    const int t = threadIdx.x;
    const int wid = t >> 6, lane = t & 63;
    const int qcol = lane & 31, h = lane >> 5;

    const int bid = blockIdx.x;
    const int bh = ((bid >> 7) << 3) | (bid & 7);    // XCD-pinned per bh
    const int p  = (bid >> 3) & 15;
    const int gA = 31 - p, gB = p;                   // pair sums to 33 steps
    const int ntA = gA + 1;                          // tiles in phase A

    const bf16* Qh = Q  + (size_t)bh * SEQ * DK;
    const bf16* Kh = K  + (size_t)bh * SEQ * DK;
    const bf16* Vh = Vt + (size_t)bh * DK * SEQ;

    // staging pointers (global side pre-swizzled; LDS dest linear)
    const int srow = t >> 3;                         // 0..15
    const int schunk = (t & 7) ^ (srow & 7);
    const bf16* kgp = Kh + (size_t)srow * DK + schunk * 8;
    const bf16* vgp = Vh + (size_t)srow * SEQ + schunk * 8;

    // per-lane ds-read byte addresses: row=qcol, slot XOR-swizzled
    const char* sbase = (const char*)&smem[0][0];
    int raddr[4];
#pragma unroll
    for (int tt = 0; tt < 4; tt++)
        raddr[tt] = qcol * 128 + (((2 * tt + h) ^ (lane & 7)) * 16);

    int qw0;
    bf16x8 qf[4];
    f32x16 o[2];
    float l;

    auto initGroup = [&](int g) {
        qw0 = g * 64 + wid * 32;
#pragma unroll
        for (int tt = 0; tt < 4; tt++)
            qf[tt] = *(const bf16x8*)(Qh + (size_t)(qw0 + qcol) * DK + tt * 16 + h * 8);
        o[0] = zero16(); o[1] = zero16();
        l = 0.f;
    };

    const int b = bh >> 4, head = bh & 15;
    auto finalize = [&]() {
        float ll = l + __shfl_xor(l, 32);
        const float inv = 1.0f / ll;
        const size_t orow = ((size_t)(b * SEQ + qw0 + qcol)) * D_MODEL + head * DK;
#pragma unroll
        for (int m = 0; m < 2; m++)
#pragma unroll
            for (int q4 = 0; q4 < 4; q4++) {
                u16x4 w;
#pragma unroll
                for (int c = 0; c < 4; c++) w[c] = f2u(o[m][q4 * 4 + c] * inv);
                *(u16x4*)&attn_out[orow + m * 32 + q4 * 8 + h * 4] = w;
            }
    };

    auto stage = [&](int kb, int buf) {
#pragma unroll
        for (int c = 0; c < 4; c++) {
            __builtin_amdgcn_global_load_lds(
                (const __attribute__((address_space(1))) void*)(kgp + (size_t)(kb + c * 16) * DK),
                (__attribute__((address_space(3))) void*)(&smem[buf][t * 8 + c * 1024]), 16, 0, 0);
            __builtin_amdgcn_global_load_lds(
                (const __attribute__((address_space(1))) void*)(vgp + (size_t)c * 16 * SEQ + kb),
                (__attribute__((address_space(3))) void*)(&smem[2 + buf][t * 8 + c * 1024]), 16, 0, 0);
        }
    };

    // QK^T for one 32-wide k-tile: lane=q, reg=k
    auto qkt = [&](const char* kb_base) -> f32x16 {
        f32x16 z = zero16();
#pragma unroll
        for (int tt = 0; tt < 4; tt++) {
            bf16x8 kf = *(const bf16x8*)(kb_base + raddr[tt]);
            z = MFMA32(kf, qf[tt], z, 0, 0, 0);
        }
        return z;
    };

    // pack 8 P-floats (k-slice ks) -> B-fragment, 2 PV MFMAs
    auto pvks = [&](const f32x16& s, int b8, int ks, const char* vbase) {
        unsigned A, B, C, D;
        asm("v_cvt_pk_bf16_f32 %0, %1, %2"
            : "=v"(A) : "v"(s[b8 + 0]), "v"(s[b8 + 1]));
        asm("v_cvt_pk_bf16_f32 %0, %1, %2"
            : "=v"(B) : "v"(s[b8 + 2]), "v"(s[b8 + 3]));
        asm("v_cvt_pk_bf16_f32 %0, %1, %2"
            : "=v"(C) : "v"(s[b8 + 4]), "v"(s[b8 + 5]));
        asm("v_cvt_pk_bf16_f32 %0, %1, %2"
            : "=v"(D) : "v"(s[b8 + 6]), "v"(s[b8 + 7]));
        v2i r02 = __builtin_amdgcn_permlane32_swap((int)A, (int)C, false, false);
        v2i r13 = __builtin_amdgcn_permlane32_swap((int)B, (int)D, false, false);
        union { unsigned u[4]; bf16x8 v; } pf;
        pf.u[0] = (unsigned)r02[0];
        pf.u[1] = (unsigned)r13[0];
        pf.u[2] = (unsigned)r02[1];
        pf.u[3] = (unsigned)r13[1];
#pragma unroll
        for (int m = 0; m < 2; m++) {
            bf16x8 vf = *(const bf16x8*)(vbase + raddr[ks] + m * 4096);
            o[m] = MFMA32(vf, pf.v, o[m], 0, 0, 0);
        }
    };

    auto smaxFull = [&](f32x16& s) -> float {
#pragma unroll
        for (int r = 0; r < 16; r++) s[r] = EXP2F(s[r]);
        float s0 = (s[0] + s[1]) + (s[2] + s[3]);
        float s1 = (s[4] + s[5]) + (s[6] + s[7]);
        float s2 = (s[8] + s[9]) + (s[10] + s[11]);
        float s3 = (s[12] + s[13]) + (s[14] + s[15]);
        return (s0 + s1) + (s2 + s3);
    };

    auto compute = [&](auto curc, int kb) {
        constexpr int CUR = decltype(curc)::v;
        const char* kbase = sbase + CUR * 8192;
        const char* vbase = sbase + 16384 + CUR * 8192;
        const int rel = qw0 - kb;          // wave-uniform
        if (rel < 0) return;
        if (rel >= 64) {
            // ---- full: both tiles, no causal mask
            __builtin_amdgcn_s_setprio(1);
            f32x16 s0 = qkt(kbase);
            f32x16 s1 = qkt(kbase + 4096);
            __builtin_amdgcn_s_setprio(0);
            l += smaxFull(s0);
            __builtin_amdgcn_s_setprio(1);
            pvks(s0, 0, 0, vbase);
            pvks(s0, 8, 1, vbase);
            __builtin_amdgcn_s_setprio(0);
            l += smaxFull(s1);
            __builtin_amdgcn_s_setprio(1);
            pvks(s1, 0, 2, vbase);
            pvks(s1, 8, 3, vbase);
            __builtin_amdgcn_s_setprio(0);
        } else {
            // ---- edge: nt tiles, diagonal mask on tile n = rel>>5
            const int nt = (rel >> 5) + 1;      // 1 or 2
            f32x16 st[2];
#pragma unroll
            for (int n = 0; n < 2; n++)
                if (n < nt) st[n] = qkt(kbase + n * 4096);
            float ps = 0.f;
#pragma unroll
            for (int n = 0; n < 2; n++)
                if (n < nt) {
                    const bool diag = (rel == 32 * n);
#pragma unroll
                    for (int r = 0; r < 16; r++) {
                        float pv = EXP2F(st[n][r]);
                        if (diag) {
                            const int kloc = (r & 3) + 8 * (r >> 2) + 4 * h;
                            pv = (kloc > qcol) ? 0.f : pv;
                        }
                        st[n][r] = pv;
                    }
                    float s0 = (st[n][0] + st[n][1]) + (st[n][2] + st[n][3]);
                    float s1 = (st[n][4] + st[n][5]) + (st[n][6] + st[n][7]);
                    float s2 = (st[n][8] + st[n][9]) + (st[n][10] + st[n][11]);
                    float s3 = (st[n][12] + st[n][13]) + (st[n][14] + st[n][15]);
                    ps += (s0 + s1) + (s2 + s3);
                }
            l += ps;
#pragma unroll
            for (int ks = 0; ks < 4; ks++)
                if (ks < 2 * nt)
                    pvks(st[ks >> 1], (ks & 1) * 8, ks, vbase);
        }
    };

    auto step = [&](auto curc, int i) {
        constexpr int CUR = decltype(curc)::v;
        __syncthreads();                       // drains prev stage (vmcnt(0))
        const int nx = i + 1;
        if (nx < 33) {
            const int tnx = (nx < ntA) ? nx : nx - ntA;
            stage(tnx * 64, CUR ^ 1);
        }
        const int kb = ((i < ntA) ? i : i - ntA) * 64;
        compute(curc, kb);
        if (i == ntA - 1) { finalize(); initGroup(gB); }
    };

    stage(0, 0);
    initGroup(gA);

    step(IC<0>{}, 0);
#pragma unroll 1
    for (int ii = 0; ii < 16; ii++) {
        step(IC<1>{}, 2 * ii + 1);
        step(IC<0>{}, 2 * ii + 2);
    }
    finalize();
}

// ---------------------------------------------------------------- launch
extern "C" void kernel_launch(void* const* d_in, const int* in_sizes, int n_in,
                              void* d_out, int out_size, void* d_ws, size_t ws_size,
                              hipStream_t stream) {
    const float* X  = (const float*)d_in[0];
    const float* Wq = (const float*)d_in[1];
    const float* Wk = (const float*)d_in[2];
    const float* Wv = (const float*)d_in[3];
    const float* Wo = (const float*)d_in[4];
    float* out = (float*)d_out;
    char* ws = (char*)d_ws;

    bf16* Xb    = (bf16*)(ws);                    // 16 MB (reused as Attn)
    bf16* WqkvT = (bf16*)(ws + (16u << 20));      //  6 MB [3072][1024]
    bf16* WoT   = (bf16*)(ws + (22u << 20));      //  2 MB
    bf16* Qb    = (bf16*)(ws + (24u << 20));      // 16 MB [bh][s][dk] (pre-scaled)
    bf16* Vt    = (bf16*)(ws + (56u << 20));      // 16 MB [bh][dk][s]
    bf16* Attn  = Xb;
    bf16* Kb    = Qb + (size_t)8388608;           // fused-QK second half

    prep_kernel<<<dim3(12288), dim3(256), 0, stream>>>(X, Wq, Wk, Wv, Wo,
                                                       Xb, WqkvT, WoT);

    gemm_qkv<<<dim3(384), dim3(512), 0, stream>>>(Xb, WqkvT, Qb, Vt);

    attn_kernel<<<dim3(1024), dim3(128), 0, stream>>>(Qb, Kb, Vt, Attn);

    gemm_o<<<dim3(512), dim3(256), 0, stream>>>(Attn, WoT, out);
}

// Round 4
// 327.163 us; speedup vs baseline: 1.0540x; 1.0540x over previous
//
#include <hip/hip_runtime.h>

typedef __bf16 bf16;
typedef __attribute__((ext_vector_type(8))) __bf16 bf16x8;
typedef __attribute__((ext_vector_type(4))) float f32x4;
typedef __attribute__((ext_vector_type(16))) float f32x16;
typedef __attribute__((ext_vector_type(4))) unsigned short u16x4;
typedef __attribute__((ext_vector_type(2))) int v2i;

#define D_MODEL 1024
#define SEQ     2048
#define NB      4
#define NH      16
#define DK      64
#define MROWS   (NB * SEQ)   // 8192

#define MFMA_BF16 __builtin_amdgcn_mfma_f32_16x16x32_bf16
#define MFMA32    __builtin_amdgcn_mfma_f32_32x32x16_bf16
#define EXP2F(x) __builtin_amdgcn_exp2f(x)
#define QSCALE 0.18033688011112042f   // 0.125 * log2(e)

#define BARRIER() do { asm volatile("" ::: "memory"); \
                       __builtin_amdgcn_s_barrier();  \
                       asm volatile("" ::: "memory"); } while (0)

__device__ __forceinline__ bf16 f2b(float f) {
    union { float f; unsigned u; } c; c.f = f;
    unsigned r = (c.u + 0x7fffu + ((c.u >> 16) & 1u)) >> 16;
    union { unsigned short s; bf16 b; } o; o.s = (unsigned short)r;
    return o.b;
}
__device__ __forceinline__ unsigned short f2u(float f) {
    union { float f; unsigned u; } c; c.f = f;
    return (unsigned short)((c.u + 0x7fffu + ((c.u >> 16) & 1u)) >> 16);
}

__device__ __forceinline__ f32x16 zero16() {
    f32x16 z = {0.f,0.f,0.f,0.f,0.f,0.f,0.f,0.f,
                0.f,0.f,0.f,0.f,0.f,0.f,0.f,0.f};
    return z;
}

template <int N> struct IC { static constexpr int v = N; };

// ---------------------------------------------------------------- prep (fused)
__global__ void prep_kernel(const float* __restrict__ X,
                            const float* __restrict__ Wq, const float* __restrict__ Wk,
                            const float* __restrict__ Wv, const float* __restrict__ Wo,
                            bf16* __restrict__ Xb, bf16* __restrict__ WqkvT,
                            bf16* __restrict__ WoT) {
    __shared__ float tile[32][33];
    const int bid = blockIdx.x;
    if (bid < 8192) {
        int i = bid * 256 + threadIdx.x;
        float4 v = ((const float4*)X)[i];
        u16x4 o; o[0] = f2u(v.x); o[1] = f2u(v.y); o[2] = f2u(v.z); o[3] = f2u(v.w);
        ((u16x4*)Xb)[i] = o;
    } else {
        int r = bid - 8192;
        int w = r >> 10, tl = r & 1023;
        const float* src = (w == 0) ? Wq : (w == 1) ? Wk : (w == 2) ? Wv : Wo;
        bf16* dst = (w == 3) ? WoT : WqkvT + (size_t)w * 1024 * 1024;
        const int n0 = (tl & 31) * 32, k0 = (tl >> 5) * 32;
        const int tx = threadIdx.x & 31, ty = threadIdx.x >> 5;
#pragma unroll
        for (int i = 0; i < 4; i++)
            tile[ty + i * 8][tx] = src[(size_t)(k0 + ty + i * 8) * 1024 + n0 + tx];
        __syncthreads();
#pragma unroll
        for (int i = 0; i < 4; i++)
            dst[(size_t)(n0 + ty + i * 8) * 1024 + k0 + tx] = f2b(tile[tx][ty + i * 8]);
    }
}

// ---------------------------------------------------------------- fused QKV GEMM
// R13: 256x256 8-phase (m201 template), fixed for the R11/R12 spill.
// Root cause of R12's 178us: P0/P1 loaded ALL quad fragments (96 VGPRs live
// across 6 barriers) with a 128-arch-VGPR cap (acc=128 AGPR) -> scratch spill
// (WRITE_SIZE 49->313MB). Fix: each phase reads ONLY its own quad's subtile
// (template-faithful), quad order (r0-3,c0-1)(r0-3,c2-3)(r4-7,c0-1)(r4-7,c2-3)
// so afL dies at P1 and afH reuses its registers; peak fragment liveness 64.
// Staging: B(kt+2)->cur at P2 (B-reads done at P1), A(kt+2)->cur at P3
// (A-reads done at P2); K(t+1) was fully staged during K(t-1)/prologue.
// Steady-state s_waitcnt vmcnt(8) once per K-tile (K(t+2)'s 8 loads in
// flight), vmcnt(0) only at kt==14.
__global__ __launch_bounds__(512, 2) void gemm_qkv(const bf16* __restrict__ A,
                                                   const bf16* __restrict__ Bt,
                                                   bf16* __restrict__ outQ,
                                                   bf16* __restrict__ outV) {
    __shared__ __align__(16) char lds[131072];  // [buf][A 32K | B 32K]

    const int t = threadIdx.x;
    const int wid = t >> 6, lane = t & 63;
    const int ln = lane & 15, qd = lane >> 4;
    const int wm = wid >> 2, wn = wid & 3;      // 2 x 4 wave grid
    const int swk = ln & 7;

    // 384 blocks: bijective XCD swizzle (384 % 8 == 0)
    const int wg = (blockIdx.x & 7) * 48 + (blockIdx.x >> 3);
    const int rowb = wg & 31, colb = wg >> 5;   // 32 rows x 12 cols
    const int row0 = rowb * 256, col0 = colb * 256;
    const bool isQK = (col0 < 2048);

    // staging: global side pre-swizzled, LDS dest linear
    const int srow = t >> 3;                    // 0..63
    const int schunk = (t & 7) ^ (srow & 7);
    const bf16* ga = A  + (size_t)(row0 + srow) * 1024 + schunk * 8;
    const bf16* gb = Bt + (size_t)(col0 + srow) * 1024 + schunk * 8;

    // half-tile stage: 128 rows x 64 k = 16KB = 512 thr x 2 loads x 16B
    auto stageA = [&](int kt, int hc, int buf) {
#pragma unroll
        for (int L = 0; L < 2; L++)
            __builtin_amdgcn_global_load_lds(
                (const __attribute__((address_space(1))) void*)
                    (ga + (size_t)(hc * 128 + L * 64) * 1024 + kt * 64),
                (__attribute__((address_space(3))) void*)
                    (lds + buf * 65536 + hc * 16384 + L * 8192 + t * 16), 16, 0, 0);
    };
    auto stageB = [&](int kt, int hc, int buf) {
#pragma unroll
        for (int L = 0; L < 2; L++)
            __builtin_amdgcn_global_load_lds(
                (const __attribute__((address_space(1))) void*)
                    (gb + (size_t)(hc * 128 + L * 64) * 1024 + kt * 64),
                (__attribute__((address_space(3))) void*)
                    (lds + buf * 65536 + 32768 + hc * 16384 + L * 8192 + t * 16), 16, 0, 0);
    };

    // per-lane LDS read bases (XOR-swizzled chunk slots)
    const char* pABase = lds + (wm * 128 + ln) * 128;
    const char* pBBase = lds + 32768 + (wn * 64 + ln) * 128;
    const int cks0 = (qd ^ swk) * 16;
    const int cks1 = ((4 + qd) ^ swk) * 16;

    f32x4 acc[8][4];
#pragma unroll
    for (int i = 0; i < 8; i++)
#pragma unroll
        for (int j = 0; j < 4; j++) acc[i][j] = (f32x4){0.f, 0.f, 0.f, 0.f};

    // ---------------- prologue: K0 + K1 fully staged (16 loads)
    stageA(0, 0, 0); stageA(0, 1, 0); stageB(0, 0, 0); stageB(0, 1, 0);
    stageA(1, 0, 1); stageA(1, 1, 1); stageB(1, 0, 1); stageB(1, 1, 1);
    asm volatile("s_waitcnt vmcnt(8)" ::: "memory");   // K0 landed; K1 in flight
    BARRIER();

    auto ktile = [&](auto bufc, int kt) {
        constexpr int BUF = decltype(bufc)::v;
        const char* pa0 = pABase + BUF * 65536 + cks0;
        const char* pa1 = pABase + BUF * 65536 + cks1;
        const char* pb0 = pBBase + BUF * 65536 + cks0;
        const char* pb1 = pBBase + BUF * 65536 + cks1;

        bf16x8 afL[4][2], afH[4][2], bfr[4][2];

        // 16 MFMA: rows i0..i0+3 x cols jh*2..jh*2+1, both k-slices
        auto quad = [&](const bf16x8 (&a)[4][2], int i0, int jh) {
            __builtin_amdgcn_s_setprio(1);
            if (isQK) {
#pragma unroll
                for (int i2 = 0; i2 < 4; i2++)
#pragma unroll
                    for (int j2 = 0; j2 < 2; j2++)
#pragma unroll
                        for (int ks = 0; ks < 2; ks++)
                            acc[i0 + i2][jh * 2 + j2] =
                                MFMA_BF16(bfr[jh * 2 + j2][ks], a[i2][ks],
                                          acc[i0 + i2][jh * 2 + j2], 0, 0, 0);
            } else {
#pragma unroll
                for (int i2 = 0; i2 < 4; i2++)
#pragma unroll
                    for (int j2 = 0; j2 < 2; j2++)
#pragma unroll
                        for (int ks = 0; ks < 2; ks++)
                            acc[i0 + i2][jh * 2 + j2] =
                                MFMA_BF16(a[i2][ks], bfr[jh * 2 + j2][ks],
                                          acc[i0 + i2][jh * 2 + j2], 0, 0, 0);
            }
            __builtin_amdgcn_s_setprio(0);
        };

        // ---- P0: read afL + bfr[0..1] (12 ds_reads); quad(r0-3, c0-1)
#pragma unroll
        for (int i = 0; i < 4; i++) {
            afL[i][0] = *(const bf16x8*)(pa0 + i * 2048);
            afL[i][1] = *(const bf16x8*)(pa1 + i * 2048);
        }
#pragma unroll
        for (int j = 0; j < 2; j++) {
            bfr[j][0] = *(const bf16x8*)(pb0 + j * 2048);
            bfr[j][1] = *(const bf16x8*)(pb1 + j * 2048);
        }
        asm volatile("s_waitcnt lgkmcnt(8)" ::: "memory");
        BARRIER();
        asm volatile("s_waitcnt lgkmcnt(0)" ::: "memory");
        quad(afL, 0, 0);
        BARRIER();

        // ---- P1: read bfr[2..3] (4 ds_reads); quad(r0-3, c2-3)
#pragma unroll
        for (int j = 0; j < 2; j++) {
            bfr[2 + j][0] = *(const bf16x8*)(pb0 + (2 + j) * 2048);
            bfr[2 + j][1] = *(const bf16x8*)(pb1 + (2 + j) * 2048);
        }
        BARRIER();
        asm volatile("s_waitcnt lgkmcnt(0)" ::: "memory");
        quad(afL, 0, 1);
        BARRIER();

        // ---- P2: read afH (8 ds_reads); stage B(kt+2)->BUF (B reads done);
        //          quad(r4-7, c0-1)
#pragma unroll
        for (int i = 0; i < 4; i++) {
            afH[i][0] = *(const bf16x8*)(pa0 + (4 + i) * 2048);
            afH[i][1] = *(const bf16x8*)(pa1 + (4 + i) * 2048);
        }
        if (kt + 2 < 16) { stageB(kt + 2, 0, BUF); stageB(kt + 2, 1, BUF); }
        BARRIER();
        asm volatile("s_waitcnt lgkmcnt(0)" ::: "memory");
        quad(afH, 4, 0);
        BARRIER();

        // ---- P3: stage A(kt+2)->BUF (A reads done); quad(r4-7, c2-3);
        //          counted vmcnt; barrier
        if (kt + 2 < 16) { stageA(kt + 2, 0, BUF); stageA(kt + 2, 1, BUF); }
        BARRIER();
        quad(afH, 4, 1);
        if (kt + 2 < 16) {
            asm volatile("s_waitcnt vmcnt(8)" ::: "memory");  // K(t+1) landed; K(t+2) in flight
        } else if (kt + 1 < 16) {
            asm volatile("s_waitcnt vmcnt(0)" ::: "memory");  // K15 must land
        }
        BARRIER();
    };

#pragma unroll 1
    for (int kt = 0; kt < 16; kt += 2) {
        ktile(IC<0>{}, kt);
        ktile(IC<1>{}, kt + 1);
    }

    // ---------------- epilogue
    if (isQK) {
#pragma unroll
        for (int i = 0; i < 8; i++)
#pragma unroll
            for (int j = 0; j < 4; j++) {
                int m  = row0 + wm * 128 + i * 16 + ln;
                int n0 = col0 + wn * 64 + j * 16 + qd * 4;
                float scale = (n0 < 1024) ? QSCALE : 1.0f;
                int b = m >> 11, s = m & 2047;
                int h = (n0 & 1023) >> 6, d0 = n0 & 63;
                size_t addr = (((size_t)(b * NH + h) * SEQ + s) * DK + d0)
                              + (size_t)(n0 >> 10) * 8388608;
                u16x4 w;
#pragma unroll
                for (int r = 0; r < 4; r++) w[r] = f2u(acc[i][j][r] * scale);
                *(u16x4*)&outQ[addr] = w;
            }
    } else {
#pragma unroll
        for (int i = 0; i < 8; i++)
#pragma unroll
            for (int j = 0; j < 4; j++) {
                int m0 = row0 + wm * 128 + i * 16 + qd * 4;
                int n  = col0 + wn * 64 + j * 16 + ln - 2048;
                int b = m0 >> 11, s0 = m0 & 2047;
                int h = n >> 6, d = n & 63;
                size_t addr = ((size_t)(b * NH + h) * DK + d) * SEQ + s0;
                u16x4 w;
#pragma unroll
                for (int r = 0; r < 4; r++) w[r] = f2u(acc[i][j][r]);
                *(u16x4*)&outV[addr] = w;
            }
    }
}

// ---------------------------------------------------------------- output GEMM
__global__ __launch_bounds__(256) void gemm_o(const bf16* __restrict__ A,
                                              const bf16* __restrict__ Bt,
                                              float* __restrict__ out) {
    __shared__ __align__(16) bf16 lA[128 * 64];
    __shared__ __align__(16) bf16 lB[128 * 64];

    const int t = threadIdx.x;
    const int wid = t >> 6, lane = t & 63;
    const int ln = lane & 15, qd = lane >> 4;
    const int wm = wid >> 1, wn = wid & 1;

    const int bid = blockIdx.x;
    const int colb = bid & 7, rowb = bid >> 3;
    const int row0 = rowb * 128, col0 = colb * 128;

    const int srow = t >> 3;
    const int schunk = (t & 7) ^ (srow & 7);
    const bf16* ga = A  + (size_t)(row0 + srow) * 1024 + schunk * 8;
    const bf16* gb = Bt + (size_t)(col0 + srow) * 1024 + schunk * 8;
    const int swk = ln & 7;

    f32x4 acc[4][4];
#pragma unroll
    for (int i = 0; i < 4; i++)
#pragma unroll
        for (int j = 0; j < 4; j++) acc[i][j] = (f32x4){0.f, 0.f, 0.f, 0.f};

    for (int kb = 0; kb < 1024; kb += 64) {
#pragma unroll
        for (int c = 0; c < 4; c++) {
            __builtin_amdgcn_global_load_lds(
                (const __attribute__((address_space(1))) void*)(ga + kb + (size_t)c * 32 * 1024),
                (__attribute__((address_space(3))) void*)(&lA[t * 8 + c * 2048]), 16, 0, 0);
            __builtin_amdgcn_global_load_lds(
                (const __attribute__((address_space(1))) void*)(gb + kb + (size_t)c * 32 * 1024),
                (__attribute__((address_space(3))) void*)(&lB[t * 8 + c * 2048]), 16, 0, 0);
        }
        __syncthreads();

#pragma unroll
        for (int ks = 0; ks < 2; ks++) {
            bf16x8 af[4], bfr[4];
#pragma unroll
            for (int i = 0; i < 4; i++)
                af[i] = *(const bf16x8*)&lA[(wm * 64 + i * 16 + ln) * 64
                                            + ((ks * 4 + qd) ^ swk) * 8];
#pragma unroll
            for (int j = 0; j < 4; j++)
                bfr[j] = *(const bf16x8*)&lB[(wn * 64 + j * 16 + ln) * 64
                                             + ((ks * 4 + qd) ^ swk) * 8];
#pragma unroll
            for (int i = 0; i < 4; i++)
#pragma unroll
                for (int j = 0; j < 4; j++)
                    acc[i][j] = MFMA_BF16(bfr[j], af[i], acc[i][j], 0, 0, 0);
        }
        __syncthreads();
    }

#pragma unroll
    for (int i = 0; i < 4; i++)
#pragma unroll
        for (int j = 0; j < 4; j++) {
            int m  = row0 + wm * 64 + i * 16 + ln;
            int n0 = col0 + wn * 64 + j * 16 + qd * 4;
            *(f32x4*)&out[(size_t)m * 1024 + n0] = acc[i][j];
        }
}

// ---------------------------------------------------------------- attention
// R10 structure (unchanged): 32x32 MFMA, in-register softmax via
// cvt_pk_bf16 + permlane32_swap, 64-row q-groups paired (g, 31-g),
// 128-thread blocks, wave-uniform full/edge specialization.
__global__ __launch_bounds__(128, 2) void attn_kernel(const bf16* __restrict__ Q,
                                                      const bf16* __restrict__ K,
                                                      const bf16* __restrict__ Vt,
                                                      bf16* __restrict__ attn_out) {
    // layout: K buf0 | K buf1 | V buf0 | V buf1   (8 KB each)
    __shared__ __align__(16) bf16 smem[4][64 * 64];

    const int t = threadIdx.x;
    const int wid = t >> 6, lane = t & 63;
    const int qcol = lane & 31, h = lane >> 5;

    const int bid = blockIdx.x;
    const int bh = ((bid >> 7) << 3) | (bid & 7);    // XCD-pinned per bh
    const int p  = (bid >> 3) & 15;
    const int gA = 31 - p, gB = p;                   // pair sums to 33 steps
    const int ntA = gA + 1;                          // tiles in phase A

    const bf16* Qh = Q  + (size_t)bh * SEQ * DK;
    const bf16* Kh = K  + (size_t)bh * SEQ * DK;
    const bf16* Vh = Vt + (size_t)bh * DK * SEQ;

    // staging pointers (global side pre-swizzled; LDS dest linear)
    const int srow = t >> 3;                         // 0..15
    const int schunk = (t & 7) ^ (srow & 7);
    const bf16* kgp = Kh + (size_t)srow * DK + schunk * 8;
    const bf16* vgp = Vh + (size_t)srow * SEQ + schunk * 8;

    // per-lane ds-read byte addresses: row=qcol, slot XOR-swizzled
    const char* sbase = (const char*)&smem[0][0];
    int raddr[4];
#pragma unroll
    for (int tt = 0; tt < 4; tt++)
        raddr[tt] = qcol * 128 + (((2 * tt + h) ^ (lane & 7)) * 16);

    int qw0;
    bf16x8 qf[4];
    f32x16 o[2];
    float l;

    auto initGroup = [&](int g) {
        qw0 = g * 64 + wid * 32;
#pragma unroll
        for (int tt = 0; tt < 4; tt++)
            qf[tt] = *(const bf16x8*)(Qh + (size_t)(qw0 + qcol) * DK + tt * 16 + h * 8);
        o[0] = zero16(); o[1] = zero16();
        l = 0.f;
    };

    const int b = bh >> 4, head = bh & 15;
    auto finalize = [&]() {
        float ll = l + __shfl_xor(l, 32);
        const float inv = 1.0f / ll;
        const size_t orow = ((size_t)(b * SEQ + qw0 + qcol)) * D_MODEL + head * DK;
#pragma unroll
        for (int m = 0; m < 2; m++)
#pragma unroll
            for (int q4 = 0; q4 < 4; q4++) {
                u16x4 w;
#pragma unroll
                for (int c = 0; c < 4; c++) w[c] = f2u(o[m][q4 * 4 + c] * inv);
                *(u16x4*)&attn_out[orow + m * 32 + q4 * 8 + h * 4] = w;
            }
    };

    auto stage = [&](int kb, int buf) {
#pragma unroll
        for (int c = 0; c < 4; c++) {
            __builtin_amdgcn_global_load_lds(
                (const __attribute__((address_space(1))) void*)(kgp + (size_t)(kb + c * 16) * DK),
                (__attribute__((address_space(3))) void*)(&smem[buf][t * 8 + c * 1024]), 16, 0, 0);
            __builtin_amdgcn_global_load_lds(
                (const __attribute__((address_space(1))) void*)(vgp + (size_t)c * 16 * SEQ + kb),
                (__attribute__((address_space(3))) void*)(&smem[2 + buf][t * 8 + c * 1024]), 16, 0, 0);
        }
    };

    // QK^T for one 32-wide k-tile: lane=q, reg=k
    auto qkt = [&](const char* kb_base) -> f32x16 {
        f32x16 z = zero16();
#pragma unroll
        for (int tt = 0; tt < 4; tt++) {
            bf16x8 kf = *(const bf16x8*)(kb_base + raddr[tt]);
            z = MFMA32(kf, qf[tt], z, 0, 0, 0);
        }
        return z;
    };

    // pack 8 P-floats (k-slice ks) -> B-fragment, 2 PV MFMAs
    auto pvks = [&](const f32x16& s, int b8, int ks, const char* vbase) {
        unsigned A, B, C, D;
        asm("v_cvt_pk_bf16_f32 %0, %1, %2"
            : "=v"(A) : "v"(s[b8 + 0]), "v"(s[b8 + 1]));
        asm("v_cvt_pk_bf16_f32 %0, %1, %2"
            : "=v"(B) : "v"(s[b8 + 2]), "v"(s[b8 + 3]));
        asm("v_cvt_pk_bf16_f32 %0, %1, %2"
            : "=v"(C) : "v"(s[b8 + 4]), "v"(s[b8 + 5]));
        asm("v_cvt_pk_bf16_f32 %0, %1, %2"
            : "=v"(D) : "v"(s[b8 + 6]), "v"(s[b8 + 7]));
        v2i r02 = __builtin_amdgcn_permlane32_swap((int)A, (int)C, false, false);
        v2i r13 = __builtin_amdgcn_permlane32_swap((int)B, (int)D, false, false);
        union { unsigned u[4]; bf16x8 v; } pf;
        pf.u[0] = (unsigned)r02[0];
        pf.u[1] = (unsigned)r13[0];
        pf.u[2] = (unsigned)r02[1];
        pf.u[3] = (unsigned)r13[1];
#pragma unroll
        for (int m = 0; m < 2; m++) {
            bf16x8 vf = *(const bf16x8*)(vbase + raddr[ks] + m * 4096);
            o[m] = MFMA32(vf, pf.v, o[m], 0, 0, 0);
        }
    };

    auto smaxFull = [&](f32x16& s) -> float {
#pragma unroll
        for (int r = 0; r < 16; r++) s[r] = EXP2F(s[r]);
        float s0 = (s[0] + s[1]) + (s[2] + s[3]);
        float s1 = (s[4] + s[5]) + (s[6] + s[7]);
        float s2 = (s[8] + s[9]) + (s[10] + s[11]);
        float s3 = (s[12] + s[13]) + (s[14] + s[15]);
        return (s0 + s1) + (s2 + s3);
    };

    auto compute = [&](auto curc, int kb) {
        constexpr int CUR = decltype(curc)::v;
        const char* kbase = sbase + CUR * 8192;
        const char* vbase = sbase + 16384 + CUR * 8192;
        const int rel = qw0 - kb;          // wave-uniform
        if (rel < 0) return;
        if (rel >= 64) {
            // ---- full: both tiles, no causal mask
            __builtin_amdgcn_s_setprio(1);
            f32x16 s0 = qkt(kbase);
            f32x16 s1 = qkt(kbase + 4096);
            __builtin_amdgcn_s_setprio(0);
            l += smaxFull(s0);
            __builtin_amdgcn_s_setprio(1);
            pvks(s0, 0, 0, vbase);
            pvks(s0, 8, 1, vbase);
            __builtin_amdgcn_s_setprio(0);
            l += smaxFull(s1);
            __builtin_amdgcn_s_setprio(1);
            pvks(s1, 0, 2, vbase);
            pvks(s1, 8, 3, vbase);
            __builtin_amdgcn_s_setprio(0);
        } else {
            // ---- edge: nt tiles, diagonal mask on tile n = rel>>5
            const int nt = (rel >> 5) + 1;      // 1 or 2
            f32x16 st[2];
#pragma unroll
            for (int n = 0; n < 2; n++)
                if (n < nt) st[n] = qkt(kbase + n * 4096);
            float ps = 0.f;
#pragma unroll
            for (int n = 0; n < 2; n++)
                if (n < nt) {
                    const bool diag = (rel == 32 * n);
#pragma unroll
                    for (int r = 0; r < 16; r++) {
                        float pv = EXP2F(st[n][r]);
                        if (diag) {
                            const int kloc = (r & 3) + 8 * (r >> 2) + 4 * h;
                            pv = (kloc > qcol) ? 0.f : pv;
                        }
                        st[n][r] = pv;
                    }
                    float s0 = (st[n][0] + st[n][1]) + (st[n][2] + st[n][3]);
                    float s1 = (st[n][4] + st[n][5]) + (st[n][6] + st[n][7]);
                    float s2 = (st[n][8] + st[n][9]) + (st[n][10] + st[n][11]);
                    float s3 = (st[n][12] + st[n][13]) + (st[n][14] + st[n][15]);
                    ps += (s0 + s1) + (s2 + s3);
                }
            l += ps;
#pragma unroll
            for (int ks = 0; ks < 4; ks++)
                if (ks < 2 * nt)
                    pvks(st[ks >> 1], (ks & 1) * 8, ks, vbase);
        }
    };

    auto step = [&](auto curc, int i) {
        constexpr int CUR = decltype(curc)::v;
        __syncthreads();                       // drains prev stage (vmcnt(0))
        const int nx = i + 1;
        if (nx < 33) {
            const int tnx = (nx < ntA) ? nx : nx - ntA;
            stage(tnx * 64, CUR ^ 1);
        }
        const int kb = ((i < ntA) ? i : i - ntA) * 64;
        compute(curc, kb);
        if (i == ntA - 1) { finalize(); initGroup(gB); }
    };

    stage(0, 0);
    initGroup(gA);

    step(IC<0>{}, 0);
#pragma unroll 1
    for (int ii = 0; ii < 16; ii++) {
        step(IC<1>{}, 2 * ii + 1);
        step(IC<0>{}, 2 * ii + 2);
    }
    finalize();
}

// ---------------------------------------------------------------- launch
extern "C" void kernel_launch(void* const* d_in, const int* in_sizes, int n_in,
                              void* d_out, int out_size, void* d_ws, size_t ws_size,
                              hipStream_t stream) {
    const float* X  = (const float*)d_in[0];
    const float* Wq = (const float*)d_in[1];
    const float* Wk = (const float*)d_in[2];
    const float* Wv = (const float*)d_in[3];
    const float* Wo = (const float*)d_in[4];
    float* out = (float*)d_out;
    char* ws = (char*)d_ws;

    bf16* Xb    = (bf16*)(ws);                    // 16 MB (reused as Attn)
    bf16* WqkvT = (bf16*)(ws + (16u << 20));      //  6 MB [3072][1024]
    bf16* WoT   = (bf16*)(ws + (22u << 20));      //  2 MB
    bf16* Qb    = (bf16*)(ws + (24u << 20));      // 16 MB [bh][s][dk] (pre-scaled)
    bf16* Vt    = (bf16*)(ws + (56u << 20));      // 16 MB [bh][dk][s]
    bf16* Attn  = Xb;
    bf16* Kb    = Qb + (size_t)8388608;           // fused-QK second half

    prep_kernel<<<dim3(12288), dim3(256), 0, stream>>>(X, Wq, Wk, Wv, Wo,
                                                       Xb, WqkvT, WoT);

    gemm_qkv<<<dim3(384), dim3(512), 0, stream>>>(Xb, WqkvT, Qb, Vt);

    attn_kernel<<<dim3(1024), dim3(128), 0, stream>>>(Qb, Kb, Vt, Attn);

    gemm_o<<<dim3(512), dim3(256), 0, stream>>>(Attn, WoT, out);
}

// Round 5
// 253.031 us; speedup vs baseline: 1.3628x; 1.2930x over previous
//
#include <hip/hip_runtime.h>

typedef __bf16 bf16;
typedef __attribute__((ext_vector_type(8))) __bf16 bf16x8;
typedef __attribute__((ext_vector_type(4))) float f32x4;
typedef __attribute__((ext_vector_type(16))) float f32x16;
typedef __attribute__((ext_vector_type(4))) unsigned short u16x4;
typedef __attribute__((ext_vector_type(2))) int v2i;

#define D_MODEL 1024
#define SEQ     2048
#define NB      4
#define NH      16
#define DK      64
#define MROWS   (NB * SEQ)   // 8192

#define MFMA_BF16 __builtin_amdgcn_mfma_f32_16x16x32_bf16
#define MFMA32    __builtin_amdgcn_mfma_f32_32x32x16_bf16
#define EXP2F(x) __builtin_amdgcn_exp2f(x)
#define QSCALE 0.18033688011112042f   // 0.125 * log2(e)

#define BARRIER() do { asm volatile("" ::: "memory"); \
                       __builtin_amdgcn_s_barrier();  \
                       asm volatile("" ::: "memory"); } while (0)

__device__ __forceinline__ bf16 f2b(float f) {
    union { float f; unsigned u; } c; c.f = f;
    unsigned r = (c.u + 0x7fffu + ((c.u >> 16) & 1u)) >> 16;
    union { unsigned short s; bf16 b; } o; o.s = (unsigned short)r;
    return o.b;
}
__device__ __forceinline__ unsigned short f2u(float f) {
    union { float f; unsigned u; } c; c.f = f;
    return (unsigned short)((c.u + 0x7fffu + ((c.u >> 16) & 1u)) >> 16);
}

__device__ __forceinline__ f32x16 zero16() {
    f32x16 z = {0.f,0.f,0.f,0.f,0.f,0.f,0.f,0.f,
                0.f,0.f,0.f,0.f,0.f,0.f,0.f,0.f};
    return z;
}

template <int N> struct IC { static constexpr int v = N; };

// ---------------------------------------------------------------- prep (fused)
__global__ void prep_kernel(const float* __restrict__ X,
                            const float* __restrict__ Wq, const float* __restrict__ Wk,
                            const float* __restrict__ Wv, const float* __restrict__ Wo,
                            bf16* __restrict__ Xb, bf16* __restrict__ WqkvT,
                            bf16* __restrict__ WoT) {
    __shared__ float tile[32][33];
    const int bid = blockIdx.x;
    if (bid < 8192) {
        int i = bid * 256 + threadIdx.x;
        float4 v = ((const float4*)X)[i];
        u16x4 o; o[0] = f2u(v.x); o[1] = f2u(v.y); o[2] = f2u(v.z); o[3] = f2u(v.w);
        ((u16x4*)Xb)[i] = o;
    } else {
        int r = bid - 8192;
        int w = r >> 10, tl = r & 1023;
        const float* src = (w == 0) ? Wq : (w == 1) ? Wk : (w == 2) ? Wv : Wo;
        bf16* dst = (w == 3) ? WoT : WqkvT + (size_t)w * 1024 * 1024;
        const int n0 = (tl & 31) * 32, k0 = (tl >> 5) * 32;
        const int tx = threadIdx.x & 31, ty = threadIdx.x >> 5;
#pragma unroll
        for (int i = 0; i < 4; i++)
            tile[ty + i * 8][tx] = src[(size_t)(k0 + ty + i * 8) * 1024 + n0 + tx];
        __syncthreads();
#pragma unroll
        for (int i = 0; i < 4; i++)
            dst[(size_t)(n0 + ty + i * 8) * 1024 + k0 + tx] = f2b(tile[tx][ty + i * 8]);
    }
}

// ---------------------------------------------------------------- fused QKV GEMM
// R14: counted-vmcnt double-buffer with acc=64 geometry.
// R12/R13 post-mortem: 256x256 with 8 waves forces acc=128/wave; with the
// 256-reg/wave cap ((512,2) is mandatory for 512-thr blocks) the fragment
// working set doesn't fit -> scratch spill -> latency stalls inside barrier-
// locked phases (WRITE_SIZE 101MB vs 49 ideal, 155us). Fix geometry, keep the
// lever that pays (T4 counted vmcnt, loads never drained):
//   BM=256 BN=128 BK=64, 512 thr = 8 waves (4M x 2N), per-wave 64x64 (acc=64,
//   the proven R2 fragment pattern: af[4][2]+bfr[4][2]=64 frag VGPRs).
//   LDS 96KB: A dbuf 2x32K, B dbuf 2x16K. Grid 32x24=768 = 3 exact CU rounds.
// Per K-tile: 16 ds_read -> barrier (all waves' reads done) -> 16 MFMA ks0
//   -> stage kt+2 (6 loads, region provably read-free) -> 16 MFMA ks1
//   -> vmcnt(6) [kt+1 landed, kt+2 in flight] -> barrier.  2 barriers/K-tile,
//   vmcnt never 0 in steady state (0 only at kt==14 to land kt15).
__global__ __launch_bounds__(512, 2) void gemm_qkv(const bf16* __restrict__ A,
                                                   const bf16* __restrict__ Bt,
                                                   bf16* __restrict__ outQ,
                                                   bf16* __restrict__ outV) {
    __shared__ __align__(16) char lds[98304];   // A: 2x32K at 0, B: 2x16K at 65536

    const int t = threadIdx.x;
    const int wid = t >> 6, lane = t & 63;
    const int ln = lane & 15, qd = lane >> 4;
    const int wm = wid >> 1, wn = wid & 1;      // 4 x 2 wave grid
    const int swk = ln & 7;

    // 768 blocks: bijective XCD swizzle (768 % 8 == 0); each XCD gets 3
    // contiguous column-panels of 32 row-blocks.
    const int wg = (blockIdx.x & 7) * 96 + (blockIdx.x >> 3);
    const int rowb = wg & 31, colb = wg >> 5;   // 32 rows x 24 cols
    const int row0 = rowb * 256, col0 = colb * 128;
    const bool isQK = (col0 < 2048);

    // staging: global side pre-swizzled, LDS dest linear
    const int srow = t >> 3;                    // 0..63
    const int schunk = (t & 7) ^ (srow & 7);
    const bf16* ga = A  + (size_t)(row0 + srow) * 1024 + schunk * 8;
    const bf16* gb = Bt + (size_t)(col0 + srow) * 1024 + schunk * 8;

    auto stageA = [&](int kt, int buf) {        // 256 rows x 64 k = 32KB, 4 loads
#pragma unroll
        for (int c = 0; c < 4; c++)
            __builtin_amdgcn_global_load_lds(
                (const __attribute__((address_space(1))) void*)
                    (ga + (size_t)(c * 64) * 1024 + kt * 64),
                (__attribute__((address_space(3))) void*)
                    (lds + buf * 32768 + c * 8192 + t * 16), 16, 0, 0);
    };
    auto stageB = [&](int kt, int buf) {        // 128 rows x 64 k = 16KB, 2 loads
#pragma unroll
        for (int c = 0; c < 2; c++)
            __builtin_amdgcn_global_load_lds(
                (const __attribute__((address_space(1))) void*)
                    (gb + (size_t)(c * 64) * 1024 + kt * 64),
                (__attribute__((address_space(3))) void*)
                    (lds + 65536 + buf * 16384 + c * 8192 + t * 16), 16, 0, 0);
    };

    // per-lane LDS read bases (XOR-swizzled chunk slots, same scheme as R2)
    const char* pABase = lds + (wm * 64 + ln) * 128;
    const char* pBBase = lds + 65536 + (wn * 64 + ln) * 128;
    const int cks0 = (qd ^ swk) * 16;
    const int cks1 = ((4 + qd) ^ swk) * 16;

    f32x4 acc[4][4];
#pragma unroll
    for (int i = 0; i < 4; i++)
#pragma unroll
        for (int j = 0; j < 4; j++) acc[i][j] = (f32x4){0.f, 0.f, 0.f, 0.f};

    // ---------------- prologue: stage K0 and K1 (12 loads)
    stageA(0, 0); stageB(0, 0);
    stageA(1, 1); stageB(1, 1);
    asm volatile("s_waitcnt vmcnt(6)" ::: "memory");   // K0 landed; K1 in flight
    BARRIER();

    auto ktile = [&](auto bufc, int kt) {
        constexpr int BUF = decltype(bufc)::v;
        const char* pa0 = pABase + BUF * 32768 + cks0;
        const char* pa1 = pABase + BUF * 32768 + cks1;
        const char* pb0 = pBBase + BUF * 16384 + cks0;
        const char* pb1 = pBBase + BUF * 16384 + cks1;

        bf16x8 af[4][2], bfr[4][2];
#pragma unroll
        for (int i = 0; i < 4; i++) {
            af[i][0] = *(const bf16x8*)(pa0 + i * 2048);
            af[i][1] = *(const bf16x8*)(pa1 + i * 2048);
        }
#pragma unroll
        for (int j = 0; j < 4; j++) {
            bfr[j][0] = *(const bf16x8*)(pb0 + j * 2048);
            bfr[j][1] = *(const bf16x8*)(pb1 + j * 2048);
        }
        asm volatile("s_waitcnt lgkmcnt(0)" ::: "memory");
        __builtin_amdgcn_sched_barrier(0);
        BARRIER();   // all waves' reads of BUF done -> BUF safe to restage

        // 16 MFMA on ks0
        __builtin_amdgcn_s_setprio(1);
        if (isQK) {
#pragma unroll
            for (int i = 0; i < 4; i++)
#pragma unroll
                for (int j = 0; j < 4; j++)
                    acc[i][j] = MFMA_BF16(bfr[j][0], af[i][0], acc[i][j], 0, 0, 0);
        } else {
#pragma unroll
            for (int i = 0; i < 4; i++)
#pragma unroll
                for (int j = 0; j < 4; j++)
                    acc[i][j] = MFMA_BF16(af[i][0], bfr[j][0], acc[i][j], 0, 0, 0);
        }
        __builtin_amdgcn_s_setprio(0);

        // stage kt+2 into BUF (read-free since the barrier above)
        if (kt + 2 < 16) { stageA(kt + 2, BUF); stageB(kt + 2, BUF); }

        // 16 MFMA on ks1
        __builtin_amdgcn_s_setprio(1);
        if (isQK) {
#pragma unroll
            for (int i = 0; i < 4; i++)
#pragma unroll
                for (int j = 0; j < 4; j++)
                    acc[i][j] = MFMA_BF16(bfr[j][1], af[i][1], acc[i][j], 0, 0, 0);
        } else {
#pragma unroll
            for (int i = 0; i < 4; i++)
#pragma unroll
                for (int j = 0; j < 4; j++)
                    acc[i][j] = MFMA_BF16(af[i][1], bfr[j][1], acc[i][j], 0, 0, 0);
        }
        __builtin_amdgcn_s_setprio(0);

        // counted drain: kt+1 must be landed for the next tile; kt+2 stays
        // in flight. Never 0 in steady state.
        if (kt + 2 < 16) {
            asm volatile("s_waitcnt vmcnt(6)" ::: "memory");
        } else if (kt + 1 < 16) {
            asm volatile("s_waitcnt vmcnt(0)" ::: "memory");
        }
        BARRIER();
    };

#pragma unroll 1
    for (int kt = 0; kt < 16; kt += 2) {
        ktile(IC<0>{}, kt);
        ktile(IC<1>{}, kt + 1);
    }

    // ---------------- epilogue (R2 layout, wave grid 4Mx2N)
    if (isQK) {
#pragma unroll
        for (int i = 0; i < 4; i++)
#pragma unroll
            for (int j = 0; j < 4; j++) {
                int m  = row0 + wm * 64 + i * 16 + ln;
                int n0 = col0 + wn * 64 + j * 16 + qd * 4;
                float scale = (n0 < 1024) ? QSCALE : 1.0f;
                int b = m >> 11, s = m & 2047;
                int h = (n0 & 1023) >> 6, d0 = n0 & 63;
                size_t addr = (((size_t)(b * NH + h) * SEQ + s) * DK + d0)
                              + (size_t)(n0 >> 10) * 8388608;
                u16x4 w;
#pragma unroll
                for (int r = 0; r < 4; r++) w[r] = f2u(acc[i][j][r] * scale);
                *(u16x4*)&outQ[addr] = w;
            }
    } else {
#pragma unroll
        for (int i = 0; i < 4; i++)
#pragma unroll
            for (int j = 0; j < 4; j++) {
                int m0 = row0 + wm * 64 + i * 16 + qd * 4;
                int n  = col0 + wn * 64 + j * 16 + ln - 2048;
                int b = m0 >> 11, s0 = m0 & 2047;
                int h = n >> 6, d = n & 63;
                size_t addr = ((size_t)(b * NH + h) * DK + d) * SEQ + s0;
                u16x4 w;
#pragma unroll
                for (int r = 0; r < 4; r++) w[r] = f2u(acc[i][j][r]);
                *(u16x4*)&outV[addr] = w;
            }
    }
}

// ---------------------------------------------------------------- output GEMM
__global__ __launch_bounds__(256) void gemm_o(const bf16* __restrict__ A,
                                              const bf16* __restrict__ Bt,
                                              float* __restrict__ out) {
    __shared__ __align__(16) bf16 lA[128 * 64];
    __shared__ __align__(16) bf16 lB[128 * 64];

    const int t = threadIdx.x;
    const int wid = t >> 6, lane = t & 63;
    const int ln = lane & 15, qd = lane >> 4;
    const int wm = wid >> 1, wn = wid & 1;

    const int bid = blockIdx.x;
    const int colb = bid & 7, rowb = bid >> 3;
    const int row0 = rowb * 128, col0 = colb * 128;

    const int srow = t >> 3;
    const int schunk = (t & 7) ^ (srow & 7);
    const bf16* ga = A  + (size_t)(row0 + srow) * 1024 + schunk * 8;
    const bf16* gb = Bt + (size_t)(col0 + srow) * 1024 + schunk * 8;
    const int swk = ln & 7;

    f32x4 acc[4][4];
#pragma unroll
    for (int i = 0; i < 4; i++)
#pragma unroll
        for (int j = 0; j < 4; j++) acc[i][j] = (f32x4){0.f, 0.f, 0.f, 0.f};

    for (int kb = 0; kb < 1024; kb += 64) {
#pragma unroll
        for (int c = 0; c < 4; c++) {
            __builtin_amdgcn_global_load_lds(
                (const __attribute__((address_space(1))) void*)(ga + kb + (size_t)c * 32 * 1024),
                (__attribute__((address_space(3))) void*)(&lA[t * 8 + c * 2048]), 16, 0, 0);
            __builtin_amdgcn_global_load_lds(
                (const __attribute__((address_space(1))) void*)(gb + kb + (size_t)c * 32 * 1024),
                (__attribute__((address_space(3))) void*)(&lB[t * 8 + c * 2048]), 16, 0, 0);
        }
        __syncthreads();

#pragma unroll
        for (int ks = 0; ks < 2; ks++) {
            bf16x8 af[4], bfr[4];
#pragma unroll
            for (int i = 0; i < 4; i++)
                af[i] = *(const bf16x8*)&lA[(wm * 64 + i * 16 + ln) * 64
                                            + ((ks * 4 + qd) ^ swk) * 8];
#pragma unroll
            for (int j = 0; j < 4; j++)
                bfr[j] = *(const bf16x8*)&lB[(wn * 64 + j * 16 + ln) * 64
                                             + ((ks * 4 + qd) ^ swk) * 8];
#pragma unroll
            for (int i = 0; i < 4; i++)
#pragma unroll
                for (int j = 0; j < 4; j++)
                    acc[i][j] = MFMA_BF16(bfr[j], af[i], acc[i][j], 0, 0, 0);
        }
        __syncthreads();
    }

#pragma unroll
    for (int i = 0; i < 4; i++)
#pragma unroll
        for (int j = 0; j < 4; j++) {
            int m  = row0 + wm * 64 + i * 16 + ln;
            int n0 = col0 + wn * 64 + j * 16 + qd * 4;
            *(f32x4*)&out[(size_t)m * 1024 + n0] = acc[i][j];
        }
}

// ---------------------------------------------------------------- attention
// R10 structure (unchanged): 32x32 MFMA, in-register softmax via
// cvt_pk_bf16 + permlane32_swap, 64-row q-groups paired (g, 31-g),
// 128-thread blocks, wave-uniform full/edge specialization.
__global__ __launch_bounds__(128, 2) void attn_kernel(const bf16* __restrict__ Q,
                                                      const bf16* __restrict__ K,
                                                      const bf16* __restrict__ Vt,
                                                      bf16* __restrict__ attn_out) {
    // layout: K buf0 | K buf1 | V buf0 | V buf1   (8 KB each)
    __shared__ __align__(16) bf16 smem[4][64 * 64];

    const int t = threadIdx.x;
    const int wid = t >> 6, lane = t & 63;
    const int qcol = lane & 31, h = lane >> 5;

    const int bid = blockIdx.x;
    const int bh = ((bid >> 7) << 3) | (bid & 7);    // XCD-pinned per bh
    const int p  = (bid >> 3) & 15;
    const int gA = 31 - p, gB = p;                   // pair sums to 33 steps
    const int ntA = gA + 1;                          // tiles in phase A

    const bf16* Qh = Q  + (size_t)bh * SEQ * DK;
    const bf16* Kh = K  + (size_t)bh * SEQ * DK;
    const bf16* Vh = Vt + (size_t)bh * DK * SEQ;

    // staging pointers (global side pre-swizzled; LDS dest linear)
    const int srow = t >> 3;                         // 0..15
    const int schunk = (t & 7) ^ (srow & 7);
    const bf16* kgp = Kh + (size_t)srow * DK + schunk * 8;
    const bf16* vgp = Vh + (size_t)srow * SEQ + schunk * 8;

    // per-lane ds-read byte addresses: row=qcol, slot XOR-swizzled
    const char* sbase = (const char*)&smem[0][0];
    int raddr[4];
#pragma unroll
    for (int tt = 0; tt < 4; tt++)
        raddr[tt] = qcol * 128 + (((2 * tt + h) ^ (lane & 7)) * 16);

    int qw0;
    bf16x8 qf[4];
    f32x16 o[2];
    float l;

    auto initGroup = [&](int g) {
        qw0 = g * 64 + wid * 32;
#pragma unroll
        for (int tt = 0; tt < 4; tt++)
            qf[tt] = *(const bf16x8*)(Qh + (size_t)(qw0 + qcol) * DK + tt * 16 + h * 8);
        o[0] = zero16(); o[1] = zero16();
        l = 0.f;
    };

    const int b = bh >> 4, head = bh & 15;
    auto finalize = [&]() {
        float ll = l + __shfl_xor(l, 32);
        const float inv = 1.0f / ll;
        const size_t orow = ((size_t)(b * SEQ + qw0 + qcol)) * D_MODEL + head * DK;
#pragma unroll
        for (int m = 0; m < 2; m++)
#pragma unroll
            for (int q4 = 0; q4 < 4; q4++) {
                u16x4 w;
#pragma unroll
                for (int c = 0; c < 4; c++) w[c] = f2u(o[m][q4 * 4 + c] * inv);
                *(u16x4*)&attn_out[orow + m * 32 + q4 * 8 + h * 4] = w;
            }
    };

    auto stage = [&](int kb, int buf) {
#pragma unroll
        for (int c = 0; c < 4; c++) {
            __builtin_amdgcn_global_load_lds(
                (const __attribute__((address_space(1))) void*)(kgp + (size_t)(kb + c * 16) * DK),
                (__attribute__((address_space(3))) void*)(&smem[buf][t * 8 + c * 1024]), 16, 0, 0);
            __builtin_amdgcn_global_load_lds(
                (const __attribute__((address_space(1))) void*)(vgp + (size_t)c * 16 * SEQ + kb),
                (__attribute__((address_space(3))) void*)(&smem[2 + buf][t * 8 + c * 1024]), 16, 0, 0);
        }
    };

    // QK^T for one 32-wide k-tile: lane=q, reg=k
    auto qkt = [&](const char* kb_base) -> f32x16 {
        f32x16 z = zero16();
#pragma unroll
        for (int tt = 0; tt < 4; tt++) {
            bf16x8 kf = *(const bf16x8*)(kb_base + raddr[tt]);
            z = MFMA32(kf, qf[tt], z, 0, 0, 0);
        }
        return z;
    };

    // pack 8 P-floats (k-slice ks) -> B-fragment, 2 PV MFMAs
    auto pvks = [&](const f32x16& s, int b8, int ks, const char* vbase) {
        unsigned A, B, C, D;
        asm("v_cvt_pk_bf16_f32 %0, %1, %2"
            : "=v"(A) : "v"(s[b8 + 0]), "v"(s[b8 + 1]));
        asm("v_cvt_pk_bf16_f32 %0, %1, %2"
            : "=v"(B) : "v"(s[b8 + 2]), "v"(s[b8 + 3]));
        asm("v_cvt_pk_bf16_f32 %0, %1, %2"
            : "=v"(C) : "v"(s[b8 + 4]), "v"(s[b8 + 5]));
        asm("v_cvt_pk_bf16_f32 %0, %1, %2"
            : "=v"(D) : "v"(s[b8 + 6]), "v"(s[b8 + 7]));
        v2i r02 = __builtin_amdgcn_permlane32_swap((int)A, (int)C, false, false);
        v2i r13 = __builtin_amdgcn_permlane32_swap((int)B, (int)D, false, false);
        union { unsigned u[4]; bf16x8 v; } pf;
        pf.u[0] = (unsigned)r02[0];
        pf.u[1] = (unsigned)r13[0];
        pf.u[2] = (unsigned)r02[1];
        pf.u[3] = (unsigned)r13[1];
#pragma unroll
        for (int m = 0; m < 2; m++) {
            bf16x8 vf = *(const bf16x8*)(vbase + raddr[ks] + m * 4096);
            o[m] = MFMA32(vf, pf.v, o[m], 0, 0, 0);
        }
    };

    auto smaxFull = [&](f32x16& s) -> float {
#pragma unroll
        for (int r = 0; r < 16; r++) s[r] = EXP2F(s[r]);
        float s0 = (s[0] + s[1]) + (s[2] + s[3]);
        float s1 = (s[4] + s[5]) + (s[6] + s[7]);
        float s2 = (s[8] + s[9]) + (s[10] + s[11]);
        float s3 = (s[12] + s[13]) + (s[14] + s[15]);
        return (s0 + s1) + (s2 + s3);
    };

    auto compute = [&](auto curc, int kb) {
        constexpr int CUR = decltype(curc)::v;
        const char* kbase = sbase + CUR * 8192;
        const char* vbase = sbase + 16384 + CUR * 8192;
        const int rel = qw0 - kb;          // wave-uniform
        if (rel < 0) return;
        if (rel >= 64) {
            // ---- full: both tiles, no causal mask
            __builtin_amdgcn_s_setprio(1);
            f32x16 s0 = qkt(kbase);
            f32x16 s1 = qkt(kbase + 4096);
            __builtin_amdgcn_s_setprio(0);
            l += smaxFull(s0);
            __builtin_amdgcn_s_setprio(1);
            pvks(s0, 0, 0, vbase);
            pvks(s0, 8, 1, vbase);
            __builtin_amdgcn_s_setprio(0);
            l += smaxFull(s1);
            __builtin_amdgcn_s_setprio(1);
            pvks(s1, 0, 2, vbase);
            pvks(s1, 8, 3, vbase);
            __builtin_amdgcn_s_setprio(0);
        } else {
            // ---- edge: nt tiles, diagonal mask on tile n = rel>>5
            const int nt = (rel >> 5) + 1;      // 1 or 2
            f32x16 st[2];
#pragma unroll
            for (int n = 0; n < 2; n++)
                if (n < nt) st[n] = qkt(kbase + n * 4096);
            float ps = 0.f;
#pragma unroll
            for (int n = 0; n < 2; n++)
                if (n < nt) {
                    const bool diag = (rel == 32 * n);
#pragma unroll
                    for (int r = 0; r < 16; r++) {
                        float pv = EXP2F(st[n][r]);
                        if (diag) {
                            const int kloc = (r & 3) + 8 * (r >> 2) + 4 * h;
                            pv = (kloc > qcol) ? 0.f : pv;
                        }
                        st[n][r] = pv;
                    }
                    float s0 = (st[n][0] + st[n][1]) + (st[n][2] + st[n][3]);
                    float s1 = (st[n][4] + st[n][5]) + (st[n][6] + st[n][7]);
                    float s2 = (st[n][8] + st[n][9]) + (st[n][10] + st[n][11]);
                    float s3 = (st[n][12] + st[n][13]) + (st[n][14] + st[n][15]);
                    ps += (s0 + s1) + (s2 + s3);
                }
            l += ps;
#pragma unroll
            for (int ks = 0; ks < 4; ks++)
                if (ks < 2 * nt)
                    pvks(st[ks >> 1], (ks & 1) * 8, ks, vbase);
        }
    };

    auto step = [&](auto curc, int i) {
        constexpr int CUR = decltype(curc)::v;
        __syncthreads();                       // drains prev stage (vmcnt(0))
        const int nx = i + 1;
        if (nx < 33) {
            const int tnx = (nx < ntA) ? nx : nx - ntA;
            stage(tnx * 64, CUR ^ 1);
        }
        const int kb = ((i < ntA) ? i : i - ntA) * 64;
        compute(curc, kb);
        if (i == ntA - 1) { finalize(); initGroup(gB); }
    };

    stage(0, 0);
    initGroup(gA);

    step(IC<0>{}, 0);
#pragma unroll 1
    for (int ii = 0; ii < 16; ii++) {
        step(IC<1>{}, 2 * ii + 1);
        step(IC<0>{}, 2 * ii + 2);
    }
    finalize();
}

// ---------------------------------------------------------------- launch
extern "C" void kernel_launch(void* const* d_in, const int* in_sizes, int n_in,
                              void* d_out, int out_size, void* d_ws, size_t ws_size,
                              hipStream_t stream) {
    const float* X  = (const float*)d_in[0];
    const float* Wq = (const float*)d_in[1];
    const float* Wk = (const float*)d_in[2];
    const float* Wv = (const float*)d_in[3];
    const float* Wo = (const float*)d_in[4];
    float* out = (float*)d_out;
    char* ws = (char*)d_ws;

    bf16* Xb    = (bf16*)(ws);                    // 16 MB (reused as Attn)
    bf16* WqkvT = (bf16*)(ws + (16u << 20));      //  6 MB [3072][1024]
    bf16* WoT   = (bf16*)(ws + (22u << 20));      //  2 MB
    bf16* Qb    = (bf16*)(ws + (24u << 20));      // 16 MB [bh][s][dk] (pre-scaled)
    bf16* Vt    = (bf16*)(ws + (56u << 20));      // 16 MB [bh][dk][s]
    bf16* Attn  = Xb;
    bf16* Kb    = Qb + (size_t)8388608;           // fused-QK second half

    prep_kernel<<<dim3(12288), dim3(256), 0, stream>>>(X, Wq, Wk, Wv, Wo,
                                                       Xb, WqkvT, WoT);

    gemm_qkv<<<dim3(768), dim3(512), 0, stream>>>(Xb, WqkvT, Qb, Vt);

    attn_kernel<<<dim3(1024), dim3(128), 0, stream>>>(Qb, Kb, Vt, Attn);

    gemm_o<<<dim3(512), dim3(256), 0, stream>>>(Attn, WoT, out);
}

// Round 6
// 238.297 us; speedup vs baseline: 1.4471x; 1.0618x over previous
//
#include <hip/hip_runtime.h>

typedef __bf16 bf16;
typedef __attribute__((ext_vector_type(8))) __bf16 bf16x8;
typedef __attribute__((ext_vector_type(4))) float f32x4;
typedef __attribute__((ext_vector_type(16))) float f32x16;
typedef __attribute__((ext_vector_type(4))) unsigned short u16x4;
typedef __attribute__((ext_vector_type(2))) int v2i;

#define D_MODEL 1024
#define SEQ     2048
#define NB      4
#define NH      16
#define DK      64
#define MROWS   (NB * SEQ)   // 8192

#define MFMA_BF16 __builtin_amdgcn_mfma_f32_16x16x32_bf16
#define MFMA32    __builtin_amdgcn_mfma_f32_32x32x16_bf16
#define EXP2F(x) __builtin_amdgcn_exp2f(x)
#define QSCALE 0.18033688011112042f   // 0.125 * log2(e)

__device__ __forceinline__ bf16 f2b(float f) {
    union { float f; unsigned u; } c; c.f = f;
    unsigned r = (c.u + 0x7fffu + ((c.u >> 16) & 1u)) >> 16;
    union { unsigned short s; bf16 b; } o; o.s = (unsigned short)r;
    return o.b;
}
__device__ __forceinline__ unsigned short f2u(float f) {
    union { float f; unsigned u; } c; c.f = f;
    return (unsigned short)((c.u + 0x7fffu + ((c.u >> 16) & 1u)) >> 16);
}

__device__ __forceinline__ f32x16 zero16() {
    f32x16 z = {0.f,0.f,0.f,0.f,0.f,0.f,0.f,0.f,
                0.f,0.f,0.f,0.f,0.f,0.f,0.f,0.f};
    return z;
}

template <int N> struct IC { static constexpr int v = N; };

// ---------------------------------------------------------------- prep (fused)
__global__ void prep_kernel(const float* __restrict__ X,
                            const float* __restrict__ Wq, const float* __restrict__ Wk,
                            const float* __restrict__ Wv, const float* __restrict__ Wo,
                            bf16* __restrict__ Xb, bf16* __restrict__ WqkvT,
                            bf16* __restrict__ WoT) {
    __shared__ float tile[32][33];
    const int bid = blockIdx.x;
    if (bid < 8192) {
        int i = bid * 256 + threadIdx.x;
        float4 v = ((const float4*)X)[i];
        u16x4 o; o[0] = f2u(v.x); o[1] = f2u(v.y); o[2] = f2u(v.z); o[3] = f2u(v.w);
        ((u16x4*)Xb)[i] = o;
    } else {
        int r = bid - 8192;
        int w = r >> 10, tl = r & 1023;
        const float* src = (w == 0) ? Wq : (w == 1) ? Wk : (w == 2) ? Wv : Wo;
        bf16* dst = (w == 3) ? WoT : WqkvT + (size_t)w * 1024 * 1024;
        const int n0 = (tl & 31) * 32, k0 = (tl >> 5) * 32;
        const int tx = threadIdx.x & 31, ty = threadIdx.x >> 5;
#pragma unroll
        for (int i = 0; i < 4; i++)
            tile[ty + i * 8][tx] = src[(size_t)(k0 + ty + i * 8) * 1024 + n0 + tx];
        __syncthreads();
#pragma unroll
        for (int i = 0; i < 4; i++)
            dst[(size_t)(n0 + ty + i * 8) * 1024 + k0 + tx] = f2b(tile[tx][ty + i * 8]);
    }
}

// ---------------------------------------------------------------- fused QKV GEMM
// R15: REVERT to the R2/R8 config (proven 69.0us, 747 TF, zero spill).
// Post-mortem of R11-R14 (256-tile / counted-vmcnt attempts, 155-179us):
// (1) 256x256 w/ 8 waves forces acc=128/wave -> fragment set can't fit the
//     256-unified-reg cap -> scratch spill; (2) after fixing spill (R14,
//     WRITE=49MB ideal), the dbuf structure still lost: 96KB LDS -> 1
//     block/CU -> single lockstep barrier domain, and the read-drain pin
//     (lgkmcnt(0)+sched_barrier before MFMA) serializes ds_read ahead of
//     MFMA. The m97 single-buffer structure + ~3 blocks/CU wave-level
//     overlap is the better operating point for this kernel from HIP source.
__global__ __launch_bounds__(256) void gemm_qkv(const bf16* __restrict__ A,
                                                const bf16* __restrict__ Bt,
                                                bf16* __restrict__ outQ,
                                                bf16* __restrict__ outV) {
    __shared__ __align__(16) bf16 lA[128 * 64];
    __shared__ __align__(16) bf16 lB[128 * 64];

    const int t = threadIdx.x;
    const int wid = t >> 6, lane = t & 63;
    const int ln = lane & 15, qd = lane >> 4;
    const int wm = wid >> 1, wn = wid & 1;

    const int bid = blockIdx.x;
    const int idx = bid >> 3;
    const int colb = (bid & 7) * 3 + (idx % 3);
    const int rowb = idx / 3;
    const int row0 = rowb * 128, col0 = colb * 128;
    const bool isQK = (col0 < 2048);

    const int srow = t >> 3;
    const int schunk = (t & 7) ^ (srow & 7);
    const bf16* ga = A  + (size_t)(row0 + srow) * 1024 + schunk * 8;
    const bf16* gb = Bt + (size_t)(col0 + srow) * 1024 + schunk * 8;
    const int swk = ln & 7;

    f32x4 acc[4][4];
#pragma unroll
    for (int i = 0; i < 4; i++)
#pragma unroll
        for (int j = 0; j < 4; j++) acc[i][j] = (f32x4){0.f, 0.f, 0.f, 0.f};

    for (int kb = 0; kb < 1024; kb += 64) {
#pragma unroll
        for (int c = 0; c < 4; c++) {
            __builtin_amdgcn_global_load_lds(
                (const __attribute__((address_space(1))) void*)(ga + kb + (size_t)c * 32 * 1024),
                (__attribute__((address_space(3))) void*)(&lA[t * 8 + c * 2048]), 16, 0, 0);
            __builtin_amdgcn_global_load_lds(
                (const __attribute__((address_space(1))) void*)(gb + kb + (size_t)c * 32 * 1024),
                (__attribute__((address_space(3))) void*)(&lB[t * 8 + c * 2048]), 16, 0, 0);
        }
        __syncthreads();

#pragma unroll
        for (int ks = 0; ks < 2; ks++) {
            bf16x8 af[4], bfr[4];
#pragma unroll
            for (int i = 0; i < 4; i++)
                af[i] = *(const bf16x8*)&lA[(wm * 64 + i * 16 + ln) * 64
                                            + ((ks * 4 + qd) ^ swk) * 8];
#pragma unroll
            for (int j = 0; j < 4; j++)
                bfr[j] = *(const bf16x8*)&lB[(wn * 64 + j * 16 + ln) * 64
                                             + ((ks * 4 + qd) ^ swk) * 8];
            if (isQK) {
#pragma unroll
                for (int i = 0; i < 4; i++)
#pragma unroll
                    for (int j = 0; j < 4; j++)
                        acc[i][j] = MFMA_BF16(bfr[j], af[i], acc[i][j], 0, 0, 0);
            } else {
#pragma unroll
                for (int i = 0; i < 4; i++)
#pragma unroll
                    for (int j = 0; j < 4; j++)
                        acc[i][j] = MFMA_BF16(af[i], bfr[j], acc[i][j], 0, 0, 0);
            }
        }
        __syncthreads();
    }

    if (isQK) {
#pragma unroll
        for (int i = 0; i < 4; i++)
#pragma unroll
            for (int j = 0; j < 4; j++) {
                int m  = row0 + wm * 64 + i * 16 + ln;
                int n0 = col0 + wn * 64 + j * 16 + qd * 4;
                float scale = (n0 < 1024) ? QSCALE : 1.0f;
                int b = m >> 11, s = m & 2047;
                int h = (n0 & 1023) >> 6, d0 = n0 & 63;
                size_t addr = (((size_t)(b * NH + h) * SEQ + s) * DK + d0)
                              + (size_t)(n0 >> 10) * 8388608;
                u16x4 w;
#pragma unroll
                for (int r = 0; r < 4; r++) w[r] = f2u(acc[i][j][r] * scale);
                *(u16x4*)&outQ[addr] = w;
            }
    } else {
#pragma unroll
        for (int i = 0; i < 4; i++)
#pragma unroll
            for (int j = 0; j < 4; j++) {
                int m0 = row0 + wm * 64 + i * 16 + qd * 4;
                int n  = col0 + wn * 64 + j * 16 + ln - 2048;
                int b = m0 >> 11, s0 = m0 & 2047;
                int h = n >> 6, d = n & 63;
                size_t addr = ((size_t)(b * NH + h) * DK + d) * SEQ + s0;
                u16x4 w;
#pragma unroll
                for (int r = 0; r < 4; r++) w[r] = f2u(acc[i][j][r]);
                *(u16x4*)&outV[addr] = w;
            }
    }
}

// ---------------------------------------------------------------- output GEMM
__global__ __launch_bounds__(256) void gemm_o(const bf16* __restrict__ A,
                                              const bf16* __restrict__ Bt,
                                              float* __restrict__ out) {
    __shared__ __align__(16) bf16 lA[128 * 64];
    __shared__ __align__(16) bf16 lB[128 * 64];

    const int t = threadIdx.x;
    const int wid = t >> 6, lane = t & 63;
    const int ln = lane & 15, qd = lane >> 4;
    const int wm = wid >> 1, wn = wid & 1;

    const int bid = blockIdx.x;
    const int colb = bid & 7, rowb = bid >> 3;
    const int row0 = rowb * 128, col0 = colb * 128;

    const int srow = t >> 3;
    const int schunk = (t & 7) ^ (srow & 7);
    const bf16* ga = A  + (size_t)(row0 + srow) * 1024 + schunk * 8;
    const bf16* gb = Bt + (size_t)(col0 + srow) * 1024 + schunk * 8;
    const int swk = ln & 7;

    f32x4 acc[4][4];
#pragma unroll
    for (int i = 0; i < 4; i++)
#pragma unroll
        for (int j = 0; j < 4; j++) acc[i][j] = (f32x4){0.f, 0.f, 0.f, 0.f};

    for (int kb = 0; kb < 1024; kb += 64) {
#pragma unroll
        for (int c = 0; c < 4; c++) {
            __builtin_amdgcn_global_load_lds(
                (const __attribute__((address_space(1))) void*)(ga + kb + (size_t)c * 32 * 1024),
                (__attribute__((address_space(3))) void*)(&lA[t * 8 + c * 2048]), 16, 0, 0);
            __builtin_amdgcn_global_load_lds(
                (const __attribute__((address_space(1))) void*)(gb + kb + (size_t)c * 32 * 1024),
                (__attribute__((address_space(3))) void*)(&lB[t * 8 + c * 2048]), 16, 0, 0);
        }
        __syncthreads();

#pragma unroll
        for (int ks = 0; ks < 2; ks++) {
            bf16x8 af[4], bfr[4];
#pragma unroll
            for (int i = 0; i < 4; i++)
                af[i] = *(const bf16x8*)&lA[(wm * 64 + i * 16 + ln) * 64
                                            + ((ks * 4 + qd) ^ swk) * 8];
#pragma unroll
            for (int j = 0; j < 4; j++)
                bfr[j] = *(const bf16x8*)&lB[(wn * 64 + j * 16 + ln) * 64
                                             + ((ks * 4 + qd) ^ swk) * 8];
#pragma unroll
            for (int i = 0; i < 4; i++)
#pragma unroll
                for (int j = 0; j < 4; j++)
                    acc[i][j] = MFMA_BF16(bfr[j], af[i], acc[i][j], 0, 0, 0);
        }
        __syncthreads();
    }

#pragma unroll
    for (int i = 0; i < 4; i++)
#pragma unroll
        for (int j = 0; j < 4; j++) {
            int m  = row0 + wm * 64 + i * 16 + ln;
            int n0 = col0 + wn * 64 + j * 16 + qd * 4;
            *(f32x4*)&out[(size_t)m * 1024 + n0] = acc[i][j];
        }
}

// ---------------------------------------------------------------- attention
// R10 structure (unchanged): 32x32 MFMA, in-register softmax via
// cvt_pk_bf16 + permlane32_swap, 64-row q-groups paired (g, 31-g),
// 128-thread blocks, wave-uniform full/edge specialization.
__global__ __launch_bounds__(128, 2) void attn_kernel(const bf16* __restrict__ Q,
                                                      const bf16* __restrict__ K,
                                                      const bf16* __restrict__ Vt,
                                                      bf16* __restrict__ attn_out) {
    // layout: K buf0 | K buf1 | V buf0 | V buf1   (8 KB each)
    __shared__ __align__(16) bf16 smem[4][64 * 64];

    const int t = threadIdx.x;
    const int wid = t >> 6, lane = t & 63;
    const int qcol = lane & 31, h = lane >> 5;

    const int bid = blockIdx.x;
    const int bh = ((bid >> 7) << 3) | (bid & 7);    // XCD-pinned per bh
    const int p  = (bid >> 3) & 15;
    const int gA = 31 - p, gB = p;                   // pair sums to 33 steps
    const int ntA = gA + 1;                          // tiles in phase A

    const bf16* Qh = Q  + (size_t)bh * SEQ * DK;
    const bf16* Kh = K  + (size_t)bh * SEQ * DK;
    const bf16* Vh = Vt + (size_t)bh * DK * SEQ;

    // staging pointers (global side pre-swizzled; LDS dest linear)
    const int srow = t >> 3;                         // 0..15
    const int schunk = (t & 7) ^ (srow & 7);
    const bf16* kgp = Kh + (size_t)srow * DK + schunk * 8;
    const bf16* vgp = Vh + (size_t)srow * SEQ + schunk * 8;

    // per-lane ds-read byte addresses: row=qcol, slot XOR-swizzled
    const char* sbase = (const char*)&smem[0][0];
    int raddr[4];
#pragma unroll
    for (int tt = 0; tt < 4; tt++)
        raddr[tt] = qcol * 128 + (((2 * tt + h) ^ (lane & 7)) * 16);

    int qw0;
    bf16x8 qf[4];
    f32x16 o[2];
    float l;

    auto initGroup = [&](int g) {
        qw0 = g * 64 + wid * 32;
#pragma unroll
        for (int tt = 0; tt < 4; tt++)
            qf[tt] = *(const bf16x8*)(Qh + (size_t)(qw0 + qcol) * DK + tt * 16 + h * 8);
        o[0] = zero16(); o[1] = zero16();
        l = 0.f;
    };

    const int b = bh >> 4, head = bh & 15;
    auto finalize = [&]() {
        float ll = l + __shfl_xor(l, 32);
        const float inv = 1.0f / ll;
        const size_t orow = ((size_t)(b * SEQ + qw0 + qcol)) * D_MODEL + head * DK;
#pragma unroll
        for (int m = 0; m < 2; m++)
#pragma unroll
            for (int q4 = 0; q4 < 4; q4++) {
                u16x4 w;
#pragma unroll
                for (int c = 0; c < 4; c++) w[c] = f2u(o[m][q4 * 4 + c] * inv);
                *(u16x4*)&attn_out[orow + m * 32 + q4 * 8 + h * 4] = w;
            }
    };

    auto stage = [&](int kb, int buf) {
#pragma unroll
        for (int c = 0; c < 4; c++) {
            __builtin_amdgcn_global_load_lds(
                (const __attribute__((address_space(1))) void*)(kgp + (size_t)(kb + c * 16) * DK),
                (__attribute__((address_space(3))) void*)(&smem[buf][t * 8 + c * 1024]), 16, 0, 0);
            __builtin_amdgcn_global_load_lds(
                (const __attribute__((address_space(1))) void*)(vgp + (size_t)c * 16 * SEQ + kb),
                (__attribute__((address_space(3))) void*)(&smem[2 + buf][t * 8 + c * 1024]), 16, 0, 0);
        }
    };

    // QK^T for one 32-wide k-tile: lane=q, reg=k
    auto qkt = [&](const char* kb_base) -> f32x16 {
        f32x16 z = zero16();
#pragma unroll
        for (int tt = 0; tt < 4; tt++) {
            bf16x8 kf = *(const bf16x8*)(kb_base + raddr[tt]);
            z = MFMA32(kf, qf[tt], z, 0, 0, 0);
        }
        return z;
    };

    // pack 8 P-floats (k-slice ks) -> B-fragment, 2 PV MFMAs
    auto pvks = [&](const f32x16& s, int b8, int ks, const char* vbase) {
        unsigned A, B, C, D;
        asm("v_cvt_pk_bf16_f32 %0, %1, %2"
            : "=v"(A) : "v"(s[b8 + 0]), "v"(s[b8 + 1]));
        asm("v_cvt_pk_bf16_f32 %0, %1, %2"
            : "=v"(B) : "v"(s[b8 + 2]), "v"(s[b8 + 3]));
        asm("v_cvt_pk_bf16_f32 %0, %1, %2"
            : "=v"(C) : "v"(s[b8 + 4]), "v"(s[b8 + 5]));
        asm("v_cvt_pk_bf16_f32 %0, %1, %2"
            : "=v"(D) : "v"(s[b8 + 6]), "v"(s[b8 + 7]));
        v2i r02 = __builtin_amdgcn_permlane32_swap((int)A, (int)C, false, false);
        v2i r13 = __builtin_amdgcn_permlane32_swap((int)B, (int)D, false, false);
        union { unsigned u[4]; bf16x8 v; } pf;
        pf.u[0] = (unsigned)r02[0];
        pf.u[1] = (unsigned)r13[0];
        pf.u[2] = (unsigned)r02[1];
        pf.u[3] = (unsigned)r13[1];
#pragma unroll
        for (int m = 0; m < 2; m++) {
            bf16x8 vf = *(const bf16x8*)(vbase + raddr[ks] + m * 4096);
            o[m] = MFMA32(vf, pf.v, o[m], 0, 0, 0);
        }
    };

    auto smaxFull = [&](f32x16& s) -> float {
#pragma unroll
        for (int r = 0; r < 16; r++) s[r] = EXP2F(s[r]);
        float s0 = (s[0] + s[1]) + (s[2] + s[3]);
        float s1 = (s[4] + s[5]) + (s[6] + s[7]);
        float s2 = (s[8] + s[9]) + (s[10] + s[11]);
        float s3 = (s[12] + s[13]) + (s[14] + s[15]);
        return (s0 + s1) + (s2 + s3);
    };

    auto compute = [&](auto curc, int kb) {
        constexpr int CUR = decltype(curc)::v;
        const char* kbase = sbase + CUR * 8192;
        const char* vbase = sbase + 16384 + CUR * 8192;
        const int rel = qw0 - kb;          // wave-uniform
        if (rel < 0) return;
        if (rel >= 64) {
            // ---- full: both tiles, no causal mask
            __builtin_amdgcn_s_setprio(1);
            f32x16 s0 = qkt(kbase);
            f32x16 s1 = qkt(kbase + 4096);
            __builtin_amdgcn_s_setprio(0);
            l += smaxFull(s0);
            __builtin_amdgcn_s_setprio(1);
            pvks(s0, 0, 0, vbase);
            pvks(s0, 8, 1, vbase);
            __builtin_amdgcn_s_setprio(0);
            l += smaxFull(s1);
            __builtin_amdgcn_s_setprio(1);
            pvks(s1, 0, 2, vbase);
            pvks(s1, 8, 3, vbase);
            __builtin_amdgcn_s_setprio(0);
        } else {
            // ---- edge: nt tiles, diagonal mask on tile n = rel>>5
            const int nt = (rel >> 5) + 1;      // 1 or 2
            f32x16 st[2];
#pragma unroll
            for (int n = 0; n < 2; n++)
                if (n < nt) st[n] = qkt(kbase + n * 4096);
            float ps = 0.f;
#pragma unroll
            for (int n = 0; n < 2; n++)
                if (n < nt) {
                    const bool diag = (rel == 32 * n);
#pragma unroll
                    for (int r = 0; r < 16; r++) {
                        float pv = EXP2F(st[n][r]);
                        if (diag) {
                            const int kloc = (r & 3) + 8 * (r >> 2) + 4 * h;
                            pv = (kloc > qcol) ? 0.f : pv;
                        }
                        st[n][r] = pv;
                    }
                    float s0 = (st[n][0] + st[n][1]) + (st[n][2] + st[n][3]);
                    float s1 = (st[n][4] + st[n][5]) + (st[n][6] + st[n][7]);
                    float s2 = (st[n][8] + st[n][9]) + (st[n][10] + st[n][11]);
                    float s3 = (st[n][12] + st[n][13]) + (st[n][14] + st[n][15]);
                    ps += (s0 + s1) + (s2 + s3);
                }
            l += ps;
#pragma unroll
            for (int ks = 0; ks < 4; ks++)
                if (ks < 2 * nt)
                    pvks(st[ks >> 1], (ks & 1) * 8, ks, vbase);
        }
    };

    auto step = [&](auto curc, int i) {
        constexpr int CUR = decltype(curc)::v;
        __syncthreads();                       // drains prev stage (vmcnt(0))
        const int nx = i + 1;
        if (nx < 33) {
            const int tnx = (nx < ntA) ? nx : nx - ntA;
            stage(tnx * 64, CUR ^ 1);
        }
        const int kb = ((i < ntA) ? i : i - ntA) * 64;
        compute(curc, kb);
        if (i == ntA - 1) { finalize(); initGroup(gB); }
    };

    stage(0, 0);
    initGroup(gA);

    step(IC<0>{}, 0);
#pragma unroll 1
    for (int ii = 0; ii < 16; ii++) {
        step(IC<1>{}, 2 * ii + 1);
        step(IC<0>{}, 2 * ii + 2);
    }
    finalize();
}

// ---------------------------------------------------------------- launch
extern "C" void kernel_launch(void* const* d_in, const int* in_sizes, int n_in,
                              void* d_out, int out_size, void* d_ws, size_t ws_size,
                              hipStream_t stream) {
    const float* X  = (const float*)d_in[0];
    const float* Wq = (const float*)d_in[1];
    const float* Wk = (const float*)d_in[2];
    const float* Wv = (const float*)d_in[3];
    const float* Wo = (const float*)d_in[4];
    float* out = (float*)d_out;
    char* ws = (char*)d_ws;

    bf16* Xb    = (bf16*)(ws);                    // 16 MB (reused as Attn)
    bf16* WqkvT = (bf16*)(ws + (16u << 20));      //  6 MB [3072][1024]
    bf16* WoT   = (bf16*)(ws + (22u << 20));      //  2 MB
    bf16* Qb    = (bf16*)(ws + (24u << 20));      // 16 MB [bh][s][dk] (pre-scaled)
    bf16* Vt    = (bf16*)(ws + (56u << 20));      // 16 MB [bh][dk][s]
    bf16* Attn  = Xb;
    bf16* Kb    = Qb + (size_t)8388608;           // fused-QK second half

    prep_kernel<<<dim3(12288), dim3(256), 0, stream>>>(X, Wq, Wk, Wv, Wo,
                                                       Xb, WqkvT, WoT);

    gemm_qkv<<<dim3(1536), dim3(256), 0, stream>>>(Xb, WqkvT, Qb, Vt);

    attn_kernel<<<dim3(1024), dim3(128), 0, stream>>>(Qb, Kb, Vt, Attn);

    gemm_o<<<dim3(512), dim3(256), 0, stream>>>(Attn, WoT, out);
}